// Round 1
// baseline (630.125 us; speedup 1.0000x reference)
//
#include <hip/hip_runtime.h>
#include <cstddef>

// Problem constants (from reference)
#define B_SZ  2
#define T_SEQ 2048
#define S_SEQ 2048
#define C_EMB 1024
#define NH    16
#define HD    64

// Workspace layout (in floats)
#define OFF_Q    ((size_t)0)                    // [B*T, C]     Qfeat -> Qrot in place
#define OFF_KV   ((size_t)4194304)              // [B*S, 2C]    K(->Krot in place) | V
#define OFF_Y    ((size_t)12582912)             // [B*T, C]
#define OFF_KSUM ((size_t)16777216)             // [B, C]
#define OFF_DEN  ((size_t)16779264)             // [B, H, T]
#define OFF_M    ((size_t)16844800)             // [B*H, 64, 64]
#define OFF_TAB  ((size_t)16975872)             // [2048, 32] float2 (cos, sin)
#define WS_FLOATS ((size_t)17106944)

__device__ __forceinline__ float elu1(float v) {
    return v > 0.0f ? v + 1.0f : __expf(v);
}

// ---------------------------------------------------------------------------
// Tiled fp32 GEMM: out[M,N] = A[M,K] @ W[K,N] + bias[N], optional elu+1
// EPI: 0 = bias only; 1 = elu1 everywhere; 2 = elu1 on cols < N/2 (K half of KV)
// BM=BN=64, BK=16, 256 threads, 4x4 microtile. All dims multiples of 64.
// ---------------------------------------------------------------------------
template<int EPI>
__global__ __launch_bounds__(256) void gemm_tiled(
    const float* __restrict__ A, const float* __restrict__ W,
    const float* __restrict__ bias, float* __restrict__ out,
    int M, int N, int K)
{
    __shared__ float As[16][68];   // [k][m], padded
    __shared__ float Bs[16][68];   // [k][n], padded

    const int tid = threadIdx.x;
    const int m0 = blockIdx.y * 64;
    const int n0 = blockIdx.x * 64;
    const int tx = tid & 15;        // col group
    const int ty = tid >> 4;        // row group
    const int a_r = tid >> 2;           // 0..63
    const int a_c = (tid & 3) << 2;     // 0,4,8,12
    const int b_r = tid >> 4;           // 0..15
    const int b_c = (tid & 15) << 2;    // 0..60

    const float* Aptr = A + (size_t)(m0 + a_r) * K + a_c;
    const float* Wptr = W + (size_t)b_r * N + n0 + b_c;

    float acc[4][4] = {};

    for (int k0 = 0; k0 < K; k0 += 16) {
        float4 av = *(const float4*)(Aptr + k0);
        float4 bv = *(const float4*)(Wptr + (size_t)k0 * N);
        __syncthreads();
        As[a_c + 0][a_r] = av.x;
        As[a_c + 1][a_r] = av.y;
        As[a_c + 2][a_r] = av.z;
        As[a_c + 3][a_r] = av.w;
        *(float4*)&Bs[b_r][b_c] = bv;
        __syncthreads();
        #pragma unroll
        for (int kk = 0; kk < 16; ++kk) {
            float4 a4 = *(const float4*)&As[kk][ty << 2];
            float4 b4 = *(const float4*)&Bs[kk][tx << 2];
            float ar[4] = {a4.x, a4.y, a4.z, a4.w};
            float br[4] = {b4.x, b4.y, b4.z, b4.w};
            #pragma unroll
            for (int i = 0; i < 4; ++i)
                #pragma unroll
                for (int j = 0; j < 4; ++j)
                    acc[i][j] += ar[i] * br[j];
        }
    }

    const int col0 = n0 + (tx << 2);
    float4 bvb = *(const float4*)(bias + col0);
    float bb[4] = {bvb.x, bvb.y, bvb.z, bvb.w};
    #pragma unroll
    for (int i = 0; i < 4; ++i) {
        int row = m0 + (ty << 2) + i;
        float4 r;
        float* rp = &r.x;
        #pragma unroll
        for (int j = 0; j < 4; ++j) {
            float v = acc[i][j] + bb[j];
            if (EPI == 1) v = elu1(v);
            if (EPI == 2) { if (col0 < (N >> 1)) v = elu1(v); }  // head-aligned: all 4 same side
            rp[j] = v;
        }
        *(float4*)(out + (size_t)row * N + col0) = r;
    }
}

// ---------------------------------------------------------------------------
// RoPE cos/sin table: tab[pos*32 + i] = (cos(pos*invf[i]), sin(pos*invf[i]))
// ---------------------------------------------------------------------------
__global__ __launch_bounds__(256) void rope_table_kernel(float2* __restrict__ tab) {
    int idx = blockIdx.x * 256 + threadIdx.x;   // pos*32 + i
    int pos = idx >> 5, i = idx & 31;
    double invf = exp(-(double)i * (9.210340371976184 / 32.0));  // 10000^(-i/32)
    float arg = (float)((double)pos * invf);
    float sn, cs;
    sincosf(arg, &sn, &cs);
    tab[idx] = make_float2(cs, sn);
}

// ---------------------------------------------------------------------------
// Ksum[b, c] = sum_s Kfeat[b, s, c]   (pre-rope, post elu+1). KV row stride 2C.
// grid (C/256, B, 16 s-chunks of 128)
// ---------------------------------------------------------------------------
__global__ __launch_bounds__(256) void ksum_kernel(
    const float* __restrict__ KV, float* __restrict__ Ksum)
{
    const int c = blockIdx.x * 256 + threadIdx.x;
    const int b = blockIdx.y;
    const int s0 = blockIdx.z * 128;
    float sum = 0.0f;
    for (int s = s0; s < s0 + 128; ++s)
        sum += KV[((size_t)(b * S_SEQ + s)) * (2 * C_EMB) + c];
    atomicAdd(&Ksum[b * C_EMB + c], sum);
}

// ---------------------------------------------------------------------------
// In-place RoPE on K half of KV. Partner element is lane^32 within the wave.
// grid B*S blocks, 256 threads (4 chunks of 256 cols).
// ---------------------------------------------------------------------------
__global__ __launch_bounds__(256) void rope_k_kernel(
    float* __restrict__ KV, const float2* __restrict__ tab)
{
    const int row = blockIdx.x;             // b*S + s
    const int s = row & (S_SEQ - 1);
    const int tid = threadIdx.x;
    float* rowp = KV + (size_t)row * (2 * C_EMB);
    #pragma unroll
    for (int k = 0; k < 4; ++k) {
        int c = tid + k * 256;
        int d = c & 63;
        int i = d & 31;
        float v = rowp[c];
        float vp = __shfl_xor(v, 32);       // partner d^32, same wave
        float2 cs = tab[s * 32 + i];
        float rot = (d < 32) ? -vp : vp;
        rowp[c] = v * cs.x + rot * cs.y;
    }
}

// ---------------------------------------------------------------------------
// In-place RoPE on Q + denom[b,h,t] = dot64(Qfeat_head, Ksum_head) (pre-rope).
// grid B*T blocks, 256 threads.
// ---------------------------------------------------------------------------
__global__ __launch_bounds__(256) void rope_q_denom_kernel(
    float* __restrict__ Q, const float* __restrict__ Ksum,
    const float2* __restrict__ tab, float* __restrict__ denom)
{
    const int row = blockIdx.x;             // b*T + t
    const int b = row >> 11;
    const int t = row & (T_SEQ - 1);
    const int tid = threadIdx.x;
    const int lane = tid & 63;
    float* rowp = Q + (size_t)row * C_EMB;
    const float* ks = Ksum + b * C_EMB;
    #pragma unroll
    for (int k = 0; k < 4; ++k) {
        int c = tid + k * 256;
        int d = c & 63;
        int i = d & 31;
        float v = rowp[c];
        float p = v * ks[c];                // pre-rope feature dot Ksum
        #pragma unroll
        for (int off = 32; off > 0; off >>= 1)
            p += __shfl_xor(p, off);        // head (=wave) reduction
        float vp = __shfl_xor(v, 32);
        float2 cs = tab[t * 32 + i];
        float rot = (d < 32) ? -vp : vp;
        rowp[c] = v * cs.x + rot * cs.y;
        if (lane == 0) {
            int h = c >> 6;
            denom[((size_t)(b * NH + h)) * T_SEQ + t] = p;
        }
    }
}

// ---------------------------------------------------------------------------
// M[bh, d1, d2] = sum_s Krot[b,s,h,d1] * V[b,s,h,d2]
// grid (8 s-chunks of 256, 32 bh), 256 threads; atomicAdd accumulate.
// ---------------------------------------------------------------------------
__global__ __launch_bounds__(256) void m_kernel(
    const float* __restrict__ KV, float* __restrict__ M)
{
    const int bh = blockIdx.y;
    const int b = bh >> 4, h = bh & 15;
    const int sbase = blockIdx.x * 256;
    __shared__ float Ks[32][64];
    __shared__ float Vs[32][64];
    const int tid = threadIdx.x;
    const int d2 = tid & 63;
    const int d1b = (tid >> 6) * 16;
    float acc[16] = {};
    for (int s0 = 0; s0 < 256; s0 += 32) {
        __syncthreads();
        #pragma unroll
        for (int k = 0; k < 8; ++k) {
            int idx = tid + k * 256;
            int r = idx >> 6, cc = idx & 63;
            size_t rowoff = (size_t)(b * S_SEQ + sbase + s0 + r) * (2 * C_EMB);
            Ks[r][cc] = KV[rowoff + h * HD + cc];
            Vs[r][cc] = KV[rowoff + C_EMB + h * HD + cc];
        }
        __syncthreads();
        #pragma unroll 8
        for (int ss = 0; ss < 32; ++ss) {
            float v = Vs[ss][d2];
            #pragma unroll
            for (int j = 0; j < 16; ++j)
                acc[j] += Ks[ss][d1b + j] * v;
        }
    }
    #pragma unroll
    for (int j = 0; j < 16; ++j)
        atomicAdd(&M[((size_t)bh * 64 + d1b + j) * 64 + d2], acc[j]);
}

// ---------------------------------------------------------------------------
// Y[b, t, h*64+d] = (sum_d1 Qrot[b,t,h,d1] * M[bh,d1,d]) / denom[b,h,t]
// grid (T/64, B*H), 256 threads.
// ---------------------------------------------------------------------------
__global__ __launch_bounds__(256) void y_kernel(
    const float* __restrict__ Q, const float* __restrict__ M,
    const float* __restrict__ denom, float* __restrict__ Y)
{
    const int bh = blockIdx.y;
    const int b = bh >> 4, h = bh & 15;
    const int t0 = blockIdx.x * 64;
    __shared__ float Ml[64][64];
    __shared__ float Ql[64][64];
    __shared__ float den[64];
    const int tid = threadIdx.x;
    #pragma unroll
    for (int k = 0; k < 16; ++k) {
        int idx = tid + k * 256;
        int r = idx >> 6, d = idx & 63;
        Ml[r][d] = M[(size_t)bh * 4096 + idx];
        Ql[r][d] = Q[((size_t)(b * T_SEQ + t0 + r)) * C_EMB + h * HD + d];
    }
    if (tid < 64) den[tid] = denom[(size_t)bh * T_SEQ + t0 + tid];
    __syncthreads();
    const int d = tid & 63;
    const int rb = (tid >> 6) * 16;
    float acc[16] = {};
    for (int d1 = 0; d1 < 64; ++d1) {
        float m = Ml[d1][d];
        #pragma unroll
        for (int j = 0; j < 16; ++j)
            acc[j] += Ql[rb + j][d1] * m;
    }
    #pragma unroll
    for (int j = 0; j < 16; ++j) {
        int r = rb + j;
        Y[((size_t)(b * T_SEQ + t0 + r)) * C_EMB + h * HD + d] = acc[j] / den[r];
    }
}

// ---------------------------------------------------------------------------
extern "C" void kernel_launch(void* const* d_in, const int* in_sizes, int n_in,
                              void* d_out, int out_size, void* d_ws, size_t ws_size,
                              hipStream_t stream)
{
    const float* x      = (const float*)d_in[0];
    const float* memory = (const float*)d_in[1];
    const float* q_w    = (const float*)d_in[2];
    const float* q_b    = (const float*)d_in[3];
    const float* kv_w   = (const float*)d_in[4];
    const float* kv_b   = (const float*)d_in[5];
    const float* proj_w = (const float*)d_in[6];
    const float* proj_b = (const float*)d_in[7];

    if (ws_size < WS_FLOATS * sizeof(float)) return;  // workspace too small: fail loudly

    float*  ws   = (float*)d_ws;
    float*  Q    = ws + OFF_Q;
    float*  KV   = ws + OFF_KV;
    float*  Y    = ws + OFF_Y;
    float*  Ksum = ws + OFF_KSUM;
    float*  den  = ws + OFF_DEN;
    float*  Mm   = ws + OFF_M;
    float2* tab  = (float2*)(ws + OFF_TAB);

    // Zero accumulators (Ksum + denom + M are contiguous)
    hipMemsetAsync(Ksum, 0, (2048 + 65536 + 131072) * sizeof(float), stream);
    rope_table_kernel<<<256, 256, 0, stream>>>(tab);

    // KV = memory @ kv_w + kv_b; elu+1 on K half
    gemm_tiled<2><<<dim3(32, 64), 256, 0, stream>>>(memory, kv_w, kv_b, KV,
                                                    B_SZ * S_SEQ, 2 * C_EMB, C_EMB);
    // Q = elu+1(x @ q_w + q_b)
    gemm_tiled<1><<<dim3(16, 64), 256, 0, stream>>>(x, q_w, q_b, Q,
                                                    B_SZ * T_SEQ, C_EMB, C_EMB);
    // Ksum over s (pre-rope K)
    ksum_kernel<<<dim3(4, 2, 16), 256, 0, stream>>>(KV, Ksum);
    // RoPE K in place
    rope_k_kernel<<<B_SZ * S_SEQ, 256, 0, stream>>>(KV, tab);
    // RoPE Q in place + denom
    rope_q_denom_kernel<<<B_SZ * T_SEQ, 256, 0, stream>>>(Q, Ksum, tab, den);
    // M = Krot^T @ V per head
    m_kernel<<<dim3(8, 32), 256, 0, stream>>>(KV, Mm);
    // Y = (Qrot @ M) / denom
    y_kernel<<<dim3(32, 32), 256, 0, stream>>>(Q, Mm, den, Y);
    // out = Y @ proj_w + proj_b
    gemm_tiled<0><<<dim3(16, 64), 256, 0, stream>>>(Y, proj_w, proj_b, (float*)d_out,
                                                    B_SZ * T_SEQ, C_EMB, C_EMB);
}

// Round 2
// 330.067 us; speedup vs baseline: 1.9091x; 1.9091x over previous
//
#include <hip/hip_runtime.h>
#include <cstddef>
#include <cstdint>

// Problem constants
#define B_SZ  2
#define T_SEQ 2048
#define S_SEQ 2048
#define C_EMB 1024
#define NH    16
#define HD    64
#define KDIM  1024   // inner dim of all three GEMMs
#define MROWS 4096   // B*T == B*S

typedef __attribute__((ext_vector_type(8))) short bf16x8;
typedef __attribute__((ext_vector_type(4))) float f32x4;

// ---------------------------------------------------------------------------
// Workspace layout (float units). Aliasing:
//   R1 (xh/xl)  : dead after Q GEMM  -> reused as Yh/Yl
//   R2 (mh/ml)  : dead after KV GEMM -> reused as Q (fp32)
// ---------------------------------------------------------------------------
#define OFF_XH    ((size_t)0)           // [4096,1024] ushort -> later Yh
#define OFF_XL    ((size_t)2097152)     //                      later Yl
#define OFF_MEMH  ((size_t)4194304)     // [4096,1024] ushort -> later Q fp32 (spans MEMH+MEML)
#define OFF_MEML  ((size_t)6291456)
#define OFF_Q     ((size_t)4194304)     // alias of MEMH/MEML region: [4096,1024] fp32
#define OFF_QWH   ((size_t)8388608)     // [1024,1024] ushort (transposed [N,K])
#define OFF_QWL   ((size_t)8912896)
#define OFF_KVWH  ((size_t)9437184)     // [2048,1024] ushort
#define OFF_KVWL  ((size_t)10485760)
#define OFF_PWH   ((size_t)11534336)    // [1024,1024] ushort
#define OFF_PWL   ((size_t)12058624)
#define OFF_KV    ((size_t)12582912)    // [4096,2048] fp32
#define OFF_KSUM  ((size_t)20971520)    // [2,1024]
#define OFF_DEN   ((size_t)20973568)    // [2,16,2048]
#define OFF_M     ((size_t)21039104)    // [32,64,64]
#define OFF_TAB   ((size_t)21170176)    // [2048,32] float2
#define WS_FLOATS ((size_t)21301248)    // ~85.2 MB

__device__ __forceinline__ float elu1(float v) {
    return v > 0.0f ? v + 1.0f : __expf(v);
}

__device__ __forceinline__ unsigned short bf16_rne(float x) {
    union { float f; unsigned int u; } v; v.f = x;
    unsigned int u = v.u;
    return (unsigned short)((u + 0x7FFFu + ((u >> 16) & 1u)) >> 16);
}
__device__ __forceinline__ float bf16_to_f(unsigned short h) {
    union { unsigned int u; float f; } v; v.u = ((unsigned int)h) << 16;
    return v.f;
}

// ---------------------------------------------------------------------------
// Elementwise split: x -> hi(bf16) + lo(bf16), flat arrays, float4 vectorized
// ---------------------------------------------------------------------------
__global__ __launch_bounds__(256) void split_kernel(
    const float4* __restrict__ in, ushort4* __restrict__ hi,
    ushort4* __restrict__ lo, int n4)
{
    int i = blockIdx.x * 256 + threadIdx.x;
    if (i >= n4) return;
    float4 v = in[i];
    ushort4 h, l;
    h.x = bf16_rne(v.x); l.x = bf16_rne(v.x - bf16_to_f(h.x));
    h.y = bf16_rne(v.y); l.y = bf16_rne(v.y - bf16_to_f(h.y));
    h.z = bf16_rne(v.z); l.z = bf16_rne(v.z - bf16_to_f(h.z));
    h.w = bf16_rne(v.w); l.w = bf16_rne(v.w - bf16_to_f(h.w));
    hi[i] = h; lo[i] = l;
}

// ---------------------------------------------------------------------------
// Weight split + transpose: W[K,N] fp32 -> Wt_hi/Wt_lo[N,K] bf16. 32x32 tiles.
// ---------------------------------------------------------------------------
__global__ __launch_bounds__(256) void split_transpose_kernel(
    const float* __restrict__ W, unsigned short* __restrict__ Wth,
    unsigned short* __restrict__ Wtl, int K, int N)
{
    __shared__ float tile[32][33];
    const int k0 = blockIdx.y * 32, n0 = blockIdx.x * 32;
    const int tx = threadIdx.x & 31, ty = threadIdx.x >> 5;   // ty 0..7
    #pragma unroll
    for (int j = 0; j < 4; ++j)
        tile[ty + j * 8][tx] = W[(size_t)(k0 + ty + j * 8) * N + n0 + tx];
    __syncthreads();
    #pragma unroll
    for (int j = 0; j < 4; ++j) {
        float x = tile[tx][ty + j * 8];            // W[k0+tx][n0+ty+j*8]
        unsigned short h = bf16_rne(x);
        unsigned short l = bf16_rne(x - bf16_to_f(h));
        size_t o = (size_t)(n0 + ty + j * 8) * K + k0 + tx;
        Wth[o] = h; Wtl[o] = l;
    }
}

// ---------------------------------------------------------------------------
// bf16x3 split MFMA GEMM: out[M,N] = (Ah+Al)[M,K] @ (Bh+Bl)[K,N] + bias
// B given transposed: Bth/Btl are [N,K]. K = 1024. Tile 128x128, BK=32,
// 256 threads = 4 waves (2x2 of 64x64), 4x4 grid of 16x16x32 MFMA per wave,
// 3 MFMAs per tile-pair (hi*hi + hi*lo + lo*hi). m97-style global_load_lds.
// EPI: 0 bias; 1 elu1; 2 elu1 on cols < C_EMB (K half of KV)
// ---------------------------------------------------------------------------
template<int EPI>
__global__ __launch_bounds__(256) void gemm_mfma(
    const unsigned short* __restrict__ Ah, const unsigned short* __restrict__ Al,
    const unsigned short* __restrict__ Bth, const unsigned short* __restrict__ Btl,
    const float* __restrict__ bias, float* __restrict__ out, int N)
{
    __shared__ unsigned short lds[4 * 4096];   // 32 KB: [Ah | Al | Bh | Bl], each 128x32
    const int tid  = threadIdx.x;
    const int w    = tid >> 6;
    const int lane = tid & 63;
    const int m0 = blockIdx.y * 128, n0 = blockIdx.x * 128;
    const int wr = w >> 1, wc = w & 1;
    const int quad = lane >> 4, lrow = lane & 15;

    // staging: wave w owns one of the 4 LDS regions
    const unsigned short* src = (w == 0) ? Ah : (w == 1) ? Al : (w == 2) ? Bth : Btl;
    const int rbase = (w < 2) ? m0 : n0;
    const int srow = lane >> 2;            // 0..15
    const int scol = (lane & 3) * 8;       // 0,8,16,24
    const unsigned short* gsrc = src + (size_t)(rbase + srow) * KDIM + scol;
    unsigned short* lbase = &lds[w * 4096];

    const unsigned short* As_h = lds;
    const unsigned short* As_l = lds + 4096;
    const unsigned short* Bs_h = lds + 8192;
    const unsigned short* Bs_l = lds + 12288;

    f32x4 acc[4][4] = {};

    for (int k0 = 0; k0 < KDIM; k0 += 32) {
        #pragma unroll
        for (int i = 0; i < 8; ++i) {
            __builtin_amdgcn_global_load_lds(
                (const __attribute__((address_space(1))) unsigned int*)(gsrc + (size_t)i * 16 * KDIM + k0),
                (__attribute__((address_space(3))) unsigned int*)(lbase + i * 512),
                16, 0, 0);
        }
        __syncthreads();   // drains vmcnt: LDS tiles ready

        bf16x8 bh[4], bl[4];
        #pragma unroll
        for (int jt = 0; jt < 4; ++jt) {
            int nl = wc * 64 + jt * 16 + lrow;
            bh[jt] = *(const bf16x8*)&Bs_h[nl * 32 + quad * 8];
            bl[jt] = *(const bf16x8*)&Bs_l[nl * 32 + quad * 8];
        }
        #pragma unroll
        for (int it = 0; it < 4; ++it) {
            int ml = wr * 64 + it * 16 + lrow;
            bf16x8 ah = *(const bf16x8*)&As_h[ml * 32 + quad * 8];
            bf16x8 al = *(const bf16x8*)&As_l[ml * 32 + quad * 8];
            #pragma unroll
            for (int jt = 0; jt < 4; ++jt) {
                acc[it][jt] = __builtin_amdgcn_mfma_f32_16x16x32_bf16(ah, bh[jt], acc[it][jt], 0, 0, 0);
                acc[it][jt] = __builtin_amdgcn_mfma_f32_16x16x32_bf16(ah, bl[jt], acc[it][jt], 0, 0, 0);
                acc[it][jt] = __builtin_amdgcn_mfma_f32_16x16x32_bf16(al, bh[jt], acc[it][jt], 0, 0, 0);
            }
        }
        __syncthreads();   // protect LDS before next stage
    }

    // epilogue: C/D layout col=lane&15, row=(lane>>4)*4+reg  [m89/m91]
    #pragma unroll
    for (int jt = 0; jt < 4; ++jt) {
        int gc = n0 + wc * 64 + jt * 16 + lrow;
        float bb = bias[gc];
        #pragma unroll
        for (int it = 0; it < 4; ++it) {
            int grb = m0 + wr * 64 + it * 16 + quad * 4;
            #pragma unroll
            for (int r = 0; r < 4; ++r) {
                float v = acc[it][jt][r] + bb;
                if (EPI == 1) v = elu1(v);
                if (EPI == 2) { if (gc < C_EMB) v = elu1(v); }
                out[(size_t)(grb + r) * N + gc] = v;
            }
        }
    }
}

// ---------------------------------------------------------------------------
// RoPE cos/sin table
// ---------------------------------------------------------------------------
__global__ __launch_bounds__(256) void rope_table_kernel(float2* __restrict__ tab) {
    int idx = blockIdx.x * 256 + threadIdx.x;   // pos*32 + i
    int pos = idx >> 5, i = idx & 31;
    double invf = exp(-(double)i * (9.210340371976184 / 32.0));  // 10000^(-i/32)
    float arg = (float)((double)pos * invf);
    float sn, cs;
    sincosf(arg, &sn, &cs);
    tab[idx] = make_float2(cs, sn);
}

// ---------------------------------------------------------------------------
// Ksum[b, c] = sum_s Kfeat[b, s, c]   (pre-rope, post elu+1)
// ---------------------------------------------------------------------------
__global__ __launch_bounds__(256) void ksum_kernel(
    const float* __restrict__ KV, float* __restrict__ Ksum)
{
    const int c = blockIdx.x * 256 + threadIdx.x;
    const int b = blockIdx.y;
    const int s0 = blockIdx.z * 128;
    float sum = 0.0f;
    for (int s = s0; s < s0 + 128; ++s)
        sum += KV[((size_t)(b * S_SEQ + s)) * (2 * C_EMB) + c];
    atomicAdd(&Ksum[b * C_EMB + c], sum);
}

// ---------------------------------------------------------------------------
// In-place RoPE on K half of KV (partner = lane^32)
// ---------------------------------------------------------------------------
__global__ __launch_bounds__(256) void rope_k_kernel(
    float* __restrict__ KV, const float2* __restrict__ tab)
{
    const int row = blockIdx.x;
    const int s = row & (S_SEQ - 1);
    const int tid = threadIdx.x;
    float* rowp = KV + (size_t)row * (2 * C_EMB);
    #pragma unroll
    for (int k = 0; k < 4; ++k) {
        int c = tid + k * 256;
        int d = c & 63;
        int i = d & 31;
        float v = rowp[c];
        float vp = __shfl_xor(v, 32);
        float2 cs = tab[s * 32 + i];
        float rot = (d < 32) ? -vp : vp;
        rowp[c] = v * cs.x + rot * cs.y;
    }
}

// ---------------------------------------------------------------------------
// In-place RoPE on Q + denom[b,h,t] = dot64(Qfeat_head, Ksum_head)
// ---------------------------------------------------------------------------
__global__ __launch_bounds__(256) void rope_q_denom_kernel(
    float* __restrict__ Q, const float* __restrict__ Ksum,
    const float2* __restrict__ tab, float* __restrict__ denom)
{
    const int row = blockIdx.x;
    const int b = row >> 11;
    const int t = row & (T_SEQ - 1);
    const int tid = threadIdx.x;
    const int lane = tid & 63;
    float* rowp = Q + (size_t)row * C_EMB;
    const float* ks = Ksum + b * C_EMB;
    #pragma unroll
    for (int k = 0; k < 4; ++k) {
        int c = tid + k * 256;
        int d = c & 63;
        int i = d & 31;
        float v = rowp[c];
        float p = v * ks[c];
        #pragma unroll
        for (int off = 32; off > 0; off >>= 1)
            p += __shfl_xor(p, off);
        float vp = __shfl_xor(v, 32);
        float2 cs = tab[t * 32 + i];
        float rot = (d < 32) ? -vp : vp;
        rowp[c] = v * cs.x + rot * cs.y;
        if (lane == 0) {
            int h = c >> 6;
            denom[((size_t)(b * NH + h)) * T_SEQ + t] = p;
        }
    }
}

// ---------------------------------------------------------------------------
// M[bh, d1, d2] = sum_s Krot[b,s,h,d1] * V[b,s,h,d2]
// ---------------------------------------------------------------------------
__global__ __launch_bounds__(256) void m_kernel(
    const float* __restrict__ KV, float* __restrict__ M)
{
    const int bh = blockIdx.y;
    const int b = bh >> 4, h = bh & 15;
    const int sbase = blockIdx.x * 256;
    __shared__ float Ks[32][64];
    __shared__ float Vs[32][64];
    const int tid = threadIdx.x;
    const int d2 = tid & 63;
    const int d1b = (tid >> 6) * 16;
    float acc[16] = {};
    for (int s0 = 0; s0 < 256; s0 += 32) {
        __syncthreads();
        #pragma unroll
        for (int k = 0; k < 8; ++k) {
            int idx = tid + k * 256;
            int r = idx >> 6, cc = idx & 63;
            size_t rowoff = (size_t)(b * S_SEQ + sbase + s0 + r) * (2 * C_EMB);
            Ks[r][cc] = KV[rowoff + h * HD + cc];
            Vs[r][cc] = KV[rowoff + C_EMB + h * HD + cc];
        }
        __syncthreads();
        #pragma unroll 8
        for (int ss = 0; ss < 32; ++ss) {
            float v = Vs[ss][d2];
            #pragma unroll
            for (int j = 0; j < 16; ++j)
                acc[j] += Ks[ss][d1b + j] * v;
        }
    }
    #pragma unroll
    for (int j = 0; j < 16; ++j)
        atomicAdd(&M[((size_t)bh * 64 + d1b + j) * 64 + d2], acc[j]);
}

// ---------------------------------------------------------------------------
// Y = (Qrot @ M) / denom, emitted directly as bf16 hi/lo splits
// ---------------------------------------------------------------------------
__global__ __launch_bounds__(256) void y_kernel(
    const float* __restrict__ Q, const float* __restrict__ M,
    const float* __restrict__ denom,
    unsigned short* __restrict__ Yh, unsigned short* __restrict__ Yl)
{
    const int bh = blockIdx.y;
    const int b = bh >> 4, h = bh & 15;
    const int t0 = blockIdx.x * 64;
    __shared__ float Ml[64][64];
    __shared__ float Ql[64][64];
    __shared__ float den[64];
    const int tid = threadIdx.x;
    #pragma unroll
    for (int k = 0; k < 16; ++k) {
        int idx = tid + k * 256;
        int r = idx >> 6, d = idx & 63;
        Ml[r][d] = M[(size_t)bh * 4096 + idx];
        Ql[r][d] = Q[((size_t)(b * T_SEQ + t0 + r)) * C_EMB + h * HD + d];
    }
    if (tid < 64) den[tid] = denom[(size_t)bh * T_SEQ + t0 + tid];
    __syncthreads();
    const int d = tid & 63;
    const int rb = (tid >> 6) * 16;
    float acc[16] = {};
    for (int d1 = 0; d1 < 64; ++d1) {
        float m = Ml[d1][d];
        #pragma unroll
        for (int j = 0; j < 16; ++j)
            acc[j] += Ql[rb + j][d1] * m;
    }
    #pragma unroll
    for (int j = 0; j < 16; ++j) {
        int r = rb + j;
        float v = acc[j] / den[r];
        size_t o = ((size_t)(b * T_SEQ + t0 + r)) * C_EMB + h * HD + d;
        unsigned short hh = bf16_rne(v);
        Yh[o] = hh;
        Yl[o] = bf16_rne(v - bf16_to_f(hh));
    }
}

// ---------------------------------------------------------------------------
extern "C" void kernel_launch(void* const* d_in, const int* in_sizes, int n_in,
                              void* d_out, int out_size, void* d_ws, size_t ws_size,
                              hipStream_t stream)
{
    const float* x      = (const float*)d_in[0];
    const float* memory = (const float*)d_in[1];
    const float* q_w    = (const float*)d_in[2];
    const float* q_b    = (const float*)d_in[3];
    const float* kv_w   = (const float*)d_in[4];
    const float* kv_b   = (const float*)d_in[5];
    const float* proj_w = (const float*)d_in[6];
    const float* proj_b = (const float*)d_in[7];

    if (ws_size < WS_FLOATS * sizeof(float)) return;  // workspace too small

    float* ws = (float*)d_ws;
    unsigned short* xh   = (unsigned short*)(ws + OFF_XH);
    unsigned short* xl   = (unsigned short*)(ws + OFF_XL);
    unsigned short* mh   = (unsigned short*)(ws + OFF_MEMH);
    unsigned short* ml   = (unsigned short*)(ws + OFF_MEML);
    unsigned short* qwh  = (unsigned short*)(ws + OFF_QWH);
    unsigned short* qwl  = (unsigned short*)(ws + OFF_QWL);
    unsigned short* kvwh = (unsigned short*)(ws + OFF_KVWH);
    unsigned short* kvwl = (unsigned short*)(ws + OFF_KVWL);
    unsigned short* pwh  = (unsigned short*)(ws + OFF_PWH);
    unsigned short* pwl  = (unsigned short*)(ws + OFF_PWL);
    float*  Q    = ws + OFF_Q;       // aliases MEMH/MEML (dead after KV GEMM)
    unsigned short* Yh = xh;         // aliases XH (dead after Q GEMM)
    unsigned short* Yl = xl;
    float*  KV   = ws + OFF_KV;
    float*  Ksum = ws + OFF_KSUM;
    float*  den  = ws + OFF_DEN;
    float*  Mm   = ws + OFF_M;
    float2* tab  = (float2*)(ws + OFF_TAB);

    // Zero accumulators (Ksum + den + M contiguous)
    hipMemsetAsync(Ksum, 0, (2048 + 65536 + 131072) * sizeof(float), stream);
    rope_table_kernel<<<256, 256, 0, stream>>>(tab);

    // bf16 hi/lo splits of activations and (transposed) weights
    split_kernel<<<4096, 256, 0, stream>>>((const float4*)x, (ushort4*)xh, (ushort4*)xl, 1048576);
    split_kernel<<<4096, 256, 0, stream>>>((const float4*)memory, (ushort4*)mh, (ushort4*)ml, 1048576);
    split_transpose_kernel<<<dim3(32, 32), 256, 0, stream>>>(q_w, qwh, qwl, 1024, 1024);
    split_transpose_kernel<<<dim3(64, 32), 256, 0, stream>>>(kv_w, kvwh, kvwl, 1024, 2048);
    split_transpose_kernel<<<dim3(32, 32), 256, 0, stream>>>(proj_w, pwh, pwl, 1024, 1024);

    // KV = memory @ kv_w + kv_b; elu+1 on K half   (must finish before Q GEMM: Q aliases mem splits)
    gemm_mfma<2><<<dim3(16, 32), 256, 0, stream>>>(mh, ml, kvwh, kvwl, kv_b, KV, 2 * C_EMB);
    // Q = elu+1(x @ q_w + q_b)
    gemm_mfma<1><<<dim3(8, 32), 256, 0, stream>>>(xh, xl, qwh, qwl, q_b, Q, C_EMB);

    // linear-attention chain
    ksum_kernel<<<dim3(4, 2, 16), 256, 0, stream>>>(KV, Ksum);
    rope_k_kernel<<<B_SZ * S_SEQ, 256, 0, stream>>>(KV, tab);
    rope_q_denom_kernel<<<B_SZ * T_SEQ, 256, 0, stream>>>(Q, Ksum, tab, den);
    m_kernel<<<dim3(8, 32), 256, 0, stream>>>(KV, Mm);
    y_kernel<<<dim3(32, 32), 256, 0, stream>>>(Q, Mm, den, Yh, Yl);

    // out = Y @ proj_w + proj_b
    gemm_mfma<0><<<dim3(8, 32), 256, 0, stream>>>(Yh, Yl, pwh, pwl, proj_b, (float*)d_out, C_EMB);
}

// Round 3
// 299.428 us; speedup vs baseline: 2.1044x; 1.1023x over previous
//
#include <hip/hip_runtime.h>
#include <cstddef>
#include <cstdint>

// Problem constants
#define B_SZ  2
#define T_SEQ 2048
#define S_SEQ 2048
#define C_EMB 1024
#define NH    16
#define HD    64
#define KDIM  1024   // inner dim of the three big GEMMs

typedef __attribute__((ext_vector_type(8))) short bf16x8;
typedef __attribute__((ext_vector_type(4))) float f32x4;

// ---------------------------------------------------------------------------
// Workspace layout (float units). Aliasing:
//   xh/xl  (x splits)   : dead after Q GEMM  -> reused as Yh/Yl
//   mh/ml  (mem splits) : dead after KV GEMM -> reused as QrotH/QrotL
// ---------------------------------------------------------------------------
#define OFF_XH    ((size_t)0)           // [4096,1024] ushort  (later Yh)
#define OFF_XL    ((size_t)2097152)     //                     (later Yl)
#define OFF_MEMH  ((size_t)4194304)     // [4096,1024] ushort  (later QrotH)
#define OFF_MEML  ((size_t)6291456)     //                     (later QrotL)
#define OFF_QWH   ((size_t)8388608)     // [1024,1024] ushort (transposed [N,K])
#define OFF_QWL   ((size_t)8912896)
#define OFF_KVWH  ((size_t)9437184)     // [2048,1024] ushort
#define OFF_KVWL  ((size_t)10485760)
#define OFF_PWH   ((size_t)11534336)    // [1024,1024] ushort
#define OFF_PWL   ((size_t)12058624)
#define OFF_KTH   ((size_t)12582912)    // [2*1024, 2048] ushort  Krot^T hi
#define OFF_KTL   ((size_t)14680064)
#define OFF_VTH   ((size_t)16777216)    // [2*1024, 2048] ushort  V^T hi
#define OFF_VTL   ((size_t)18874368)
#define OFF_KSUM  ((size_t)20971520)    // [2,1024]
#define OFF_MT    ((size_t)20973568)    // [32,64,64] fp32  (Mt[d2][d1])
#define OFF_DEN   ((size_t)21104640)    // [32,2048]
#define OFF_TAB   ((size_t)21170176)    // [2048,32] float2
#define WS_FLOATS ((size_t)21301248)    // ~85.2 MB

__device__ __forceinline__ float elu1(float v) {
    return v > 0.0f ? v + 1.0f : __expf(v);
}
__device__ __forceinline__ unsigned short bf16_rne(float x) {
    union { float f; unsigned int u; } v; v.f = x;
    unsigned int u = v.u;
    return (unsigned short)((u + 0x7FFFu + ((u >> 16) & 1u)) >> 16);
}
__device__ __forceinline__ float bf16_to_f(unsigned short h) {
    union { unsigned int u; float f; } v; v.u = ((unsigned int)h) << 16;
    return v.f;
}

// ---------------------------------------------------------------------------
// Elementwise split: fp32 -> hi(bf16) + lo(bf16)
// ---------------------------------------------------------------------------
__global__ __launch_bounds__(256) void split_kernel(
    const float4* __restrict__ in, ushort4* __restrict__ hi,
    ushort4* __restrict__ lo, int n4)
{
    int i = blockIdx.x * 256 + threadIdx.x;
    if (i >= n4) return;
    float4 v = in[i];
    ushort4 h, l;
    h.x = bf16_rne(v.x); l.x = bf16_rne(v.x - bf16_to_f(h.x));
    h.y = bf16_rne(v.y); l.y = bf16_rne(v.y - bf16_to_f(h.y));
    h.z = bf16_rne(v.z); l.z = bf16_rne(v.z - bf16_to_f(h.z));
    h.w = bf16_rne(v.w); l.w = bf16_rne(v.w - bf16_to_f(h.w));
    hi[i] = h; lo[i] = l;
}

// ---------------------------------------------------------------------------
// Weight split + transpose: W[K,N] fp32 -> Wt_hi/Wt_lo[N,K] bf16
// ---------------------------------------------------------------------------
__global__ __launch_bounds__(256) void split_transpose_kernel(
    const float* __restrict__ W, unsigned short* __restrict__ Wth,
    unsigned short* __restrict__ Wtl, int K, int N)
{
    __shared__ float tile[32][33];
    const int k0 = blockIdx.y * 32, n0 = blockIdx.x * 32;
    const int tx = threadIdx.x & 31, ty = threadIdx.x >> 5;
    #pragma unroll
    for (int j = 0; j < 4; ++j)
        tile[ty + j * 8][tx] = W[(size_t)(k0 + ty + j * 8) * N + n0 + tx];
    __syncthreads();
    #pragma unroll
    for (int j = 0; j < 4; ++j) {
        float x = tile[tx][ty + j * 8];
        unsigned short h = bf16_rne(x);
        unsigned short l = bf16_rne(x - bf16_to_f(h));
        size_t o = (size_t)(n0 + ty + j * 8) * K + k0 + tx;
        Wth[o] = h; Wtl[o] = l;
    }
}

// ---------------------------------------------------------------------------
// RoPE cos/sin table
// ---------------------------------------------------------------------------
__global__ __launch_bounds__(256) void rope_table_kernel(float2* __restrict__ tab) {
    int idx = blockIdx.x * 256 + threadIdx.x;   // pos*32 + i
    int pos = idx >> 5, i = idx & 31;
    double invf = exp(-(double)i * (9.210340371976184 / 32.0));  // 10000^(-i/32)
    float arg = (float)((double)pos * invf);
    float sn, cs;
    sincosf(arg, &sn, &cs);
    tab[idx] = make_float2(cs, sn);
}

// ---------------------------------------------------------------------------
// Shared bf16x3 MFMA GEMM main loop. 128x128 tile, BK=32, 256 thr = 4 waves.
// A hi/lo [M,K]; B hi/lo given transposed [N,K]. Fills acc[4][4] (wave: 64x64).
// ---------------------------------------------------------------------------
__device__ __forceinline__ void gemm_main_loop(
    const unsigned short* __restrict__ Ah, const unsigned short* __restrict__ Al,
    const unsigned short* __restrict__ Bth, const unsigned short* __restrict__ Btl,
    unsigned short* lds, int m0, int n0, f32x4 acc[4][4])
{
    const int tid = threadIdx.x;
    const int w = tid >> 6, lane = tid & 63;
    const int wr = w >> 1, wc = w & 1;
    const int quad = lane >> 4, lrow = lane & 15;

    const unsigned short* src = (w == 0) ? Ah : (w == 1) ? Al : (w == 2) ? Bth : Btl;
    const int rbase = (w < 2) ? m0 : n0;
    const int srow = lane >> 2;
    const int scol = (lane & 3) * 8;
    const unsigned short* gsrc = src + (size_t)(rbase + srow) * KDIM + scol;
    unsigned short* lbase = &lds[w * 4096];

    const unsigned short* As_h = lds;
    const unsigned short* As_l = lds + 4096;
    const unsigned short* Bs_h = lds + 8192;
    const unsigned short* Bs_l = lds + 12288;

    for (int k0 = 0; k0 < KDIM; k0 += 32) {
        #pragma unroll
        for (int i = 0; i < 8; ++i) {
            __builtin_amdgcn_global_load_lds(
                (const __attribute__((address_space(1))) unsigned int*)(gsrc + (size_t)i * 16 * KDIM + k0),
                (__attribute__((address_space(3))) unsigned int*)(lbase + i * 512),
                16, 0, 0);
        }
        __syncthreads();

        bf16x8 bh[4], bl[4];
        #pragma unroll
        for (int jt = 0; jt < 4; ++jt) {
            int nl = wc * 64 + jt * 16 + lrow;
            bh[jt] = *(const bf16x8*)&Bs_h[nl * 32 + quad * 8];
            bl[jt] = *(const bf16x8*)&Bs_l[nl * 32 + quad * 8];
        }
        #pragma unroll
        for (int it = 0; it < 4; ++it) {
            int ml = wr * 64 + it * 16 + lrow;
            bf16x8 ah = *(const bf16x8*)&As_h[ml * 32 + quad * 8];
            bf16x8 al = *(const bf16x8*)&As_l[ml * 32 + quad * 8];
            #pragma unroll
            for (int jt = 0; jt < 4; ++jt) {
                acc[it][jt] = __builtin_amdgcn_mfma_f32_16x16x32_bf16(ah, bh[jt], acc[it][jt], 0, 0, 0);
                acc[it][jt] = __builtin_amdgcn_mfma_f32_16x16x32_bf16(ah, bl[jt], acc[it][jt], 0, 0, 0);
                acc[it][jt] = __builtin_amdgcn_mfma_f32_16x16x32_bf16(al, bh[jt], acc[it][jt], 0, 0, 0);
            }
        }
        __syncthreads();
    }
}

// ---------------------------------------------------------------------------
// KV GEMM + fused epilogue: bias, elu+1 (K half), Ksum atomics (pre-rope),
// RoPE in registers (partner = acc tile jt^2, same lane), transposed bf16
// hi/lo stores of Krot^T and V^T.  N = 2048, grid (16, 32).
// ---------------------------------------------------------------------------
__global__ __launch_bounds__(256) void gemm_kv(
    const unsigned short* __restrict__ Ah, const unsigned short* __restrict__ Al,
    const unsigned short* __restrict__ Bth, const unsigned short* __restrict__ Btl,
    const float* __restrict__ bias, const float2* __restrict__ tab,
    float* __restrict__ Ksum,
    unsigned short* __restrict__ KtH, unsigned short* __restrict__ KtL,
    unsigned short* __restrict__ VtH, unsigned short* __restrict__ VtL)
{
    __shared__ unsigned short lds[16384];
    const int m0 = blockIdx.y * 128, n0 = blockIdx.x * 128;
    f32x4 acc[4][4] = {};
    gemm_main_loop(Ah, Al, Bth, Btl, lds, m0, n0, acc);

    const int tid = threadIdx.x;
    const int w = tid >> 6, lane = tid & 63;
    const int wr = w >> 1, wc = w & 1;
    const int quad = lane >> 4, lrow = lane & 15;
    const int colbase = n0 + wc * 64;         // wave spans one full 64-col head slice
    const bool isK = colbase < C_EMB;
    const int b = m0 >> 11;
    const int tbase = (m0 & 2047) + wr * 64;

    float bb[4];
    #pragma unroll
    for (int jt = 0; jt < 4; ++jt) bb[jt] = bias[colbase + jt * 16 + lrow];
    #pragma unroll
    for (int it = 0; it < 4; ++it)
        #pragma unroll
        for (int jt = 0; jt < 4; ++jt)
            #pragma unroll
            for (int r = 0; r < 4; ++r) {
                float v = acc[it][jt][r] + bb[jt];
                acc[it][jt][r] = isK ? elu1(v) : v;
            }

    if (isK) {
        // Ksum (pre-rope): reduce 16 own values, then across quads
        #pragma unroll
        for (int jt = 0; jt < 4; ++jt) {
            float p = 0.0f;
            #pragma unroll
            for (int it = 0; it < 4; ++it)
                #pragma unroll
                for (int r = 0; r < 4; ++r) p += acc[it][jt][r];
            p += __shfl_xor(p, 16);
            p += __shfl_xor(p, 32);
            if (quad == 0)
                atomicAdd(&Ksum[b * C_EMB + colbase + jt * 16 + lrow], p);
        }
        // RoPE in registers: d = jt*16+lrow; pairs (jt, jt^2), same lane
        #pragma unroll
        for (int it = 0; it < 4; ++it)
            #pragma unroll
            for (int r = 0; r < 4; ++r) {
                int s = tbase + it * 16 + quad * 4 + r;
                float2 c0 = tab[s * 32 + lrow];
                float2 c1 = tab[s * 32 + 16 + lrow];
                float a0 = acc[it][0][r], a1 = acc[it][1][r];
                float a2 = acc[it][2][r], a3 = acc[it][3][r];
                acc[it][0][r] = a0 * c0.x - a2 * c0.y;
                acc[it][2][r] = a2 * c0.x + a0 * c0.y;
                acc[it][1][r] = a1 * c1.x - a3 * c1.y;
                acc[it][3][r] = a3 * c1.x + a1 * c1.y;
            }
    }

    unsigned short* Hd = isK ? KtH : VtH;
    unsigned short* Ld = isK ? KtL : VtL;
    const int cadj = isK ? 0 : C_EMB;
    #pragma unroll
    for (int jt = 0; jt < 4; ++jt) {
        size_t rowb = ((size_t)b * 1024 + (colbase - cadj) + jt * 16 + lrow) * 2048;
        #pragma unroll
        for (int it = 0; it < 4; ++it) {
            int sloc = tbase + it * 16 + quad * 4;
            ushort4 h4, l4;
            float v0 = acc[it][jt][0], v1 = acc[it][jt][1];
            float v2 = acc[it][jt][2], v3 = acc[it][jt][3];
            h4.x = bf16_rne(v0); l4.x = bf16_rne(v0 - bf16_to_f(h4.x));
            h4.y = bf16_rne(v1); l4.y = bf16_rne(v1 - bf16_to_f(h4.y));
            h4.z = bf16_rne(v2); l4.z = bf16_rne(v2 - bf16_to_f(h4.z));
            h4.w = bf16_rne(v3); l4.w = bf16_rne(v3 - bf16_to_f(h4.w));
            *(ushort4*)&Hd[rowb + sloc] = h4;
            *(ushort4*)&Ld[rowb + sloc] = l4;
        }
    }
}

// ---------------------------------------------------------------------------
// Q GEMM + fused epilogue: bias, elu+1, denom = (pre-rope Q).Ksum (intra-quad
// shuffle reduce), RoPE in registers, natural-layout bf16 hi/lo stores.
// N = 1024, grid (8, 32).
// ---------------------------------------------------------------------------
__global__ __launch_bounds__(256) void gemm_q(
    const unsigned short* __restrict__ Ah, const unsigned short* __restrict__ Al,
    const unsigned short* __restrict__ Bth, const unsigned short* __restrict__ Btl,
    const float* __restrict__ bias, const float2* __restrict__ tab,
    const float* __restrict__ Ksum, float* __restrict__ den,
    unsigned short* __restrict__ Qh, unsigned short* __restrict__ Ql)
{
    __shared__ unsigned short lds[16384];
    const int m0 = blockIdx.y * 128, n0 = blockIdx.x * 128;
    f32x4 acc[4][4] = {};
    gemm_main_loop(Ah, Al, Bth, Btl, lds, m0, n0, acc);

    const int tid = threadIdx.x;
    const int w = tid >> 6, lane = tid & 63;
    const int wr = w >> 1, wc = w & 1;
    const int quad = lane >> 4, lrow = lane & 15;
    const int colbase = n0 + wc * 64;
    const int h = colbase >> 6;
    const int b = m0 >> 11;
    const int tbase = (m0 & 2047) + wr * 64;

    float bb[4];
    #pragma unroll
    for (int jt = 0; jt < 4; ++jt) bb[jt] = bias[colbase + jt * 16 + lrow];
    #pragma unroll
    for (int it = 0; it < 4; ++it)
        #pragma unroll
        for (int jt = 0; jt < 4; ++jt)
            #pragma unroll
            for (int r = 0; r < 4; ++r)
                acc[it][jt][r] = elu1(acc[it][jt][r] + bb[jt]);

    // denom (pre-rope)
    float ks[4];
    #pragma unroll
    for (int jt = 0; jt < 4; ++jt) ks[jt] = Ksum[b * C_EMB + colbase + jt * 16 + lrow];
    #pragma unroll
    for (int it = 0; it < 4; ++it)
        #pragma unroll
        for (int r = 0; r < 4; ++r) {
            float p = acc[it][0][r] * ks[0] + acc[it][1][r] * ks[1]
                    + acc[it][2][r] * ks[2] + acc[it][3][r] * ks[3];
            p += __shfl_xor(p, 1);
            p += __shfl_xor(p, 2);
            p += __shfl_xor(p, 4);
            p += __shfl_xor(p, 8);
            if (lrow == 0)
                den[((size_t)(b * NH + h)) * T_SEQ + tbase + it * 16 + quad * 4 + r] = p;
        }

    // RoPE in registers
    #pragma unroll
    for (int it = 0; it < 4; ++it)
        #pragma unroll
        for (int r = 0; r < 4; ++r) {
            int s = tbase + it * 16 + quad * 4 + r;
            float2 c0 = tab[s * 32 + lrow];
            float2 c1 = tab[s * 32 + 16 + lrow];
            float a0 = acc[it][0][r], a1 = acc[it][1][r];
            float a2 = acc[it][2][r], a3 = acc[it][3][r];
            acc[it][0][r] = a0 * c0.x - a2 * c0.y;
            acc[it][2][r] = a2 * c0.x + a0 * c0.y;
            acc[it][1][r] = a1 * c1.x - a3 * c1.y;
            acc[it][3][r] = a3 * c1.x + a1 * c1.y;
        }

    // natural-layout bf16 hi/lo stores
    #pragma unroll
    for (int it = 0; it < 4; ++it)
        #pragma unroll
        for (int jt = 0; jt < 4; ++jt)
            #pragma unroll
            for (int r = 0; r < 4; ++r) {
                float v = acc[it][jt][r];
                size_t o = ((size_t)(m0 + wr * 64 + it * 16 + quad * 4 + r)) * C_EMB
                         + colbase + jt * 16 + lrow;
                unsigned short hh = bf16_rne(v);
                Qh[o] = hh;
                Ql[o] = bf16_rne(v - bf16_to_f(hh));
            }
}

// ---------------------------------------------------------------------------
// Mt[bh][d2][d1] = sum_s V[s,d2]*Krot[s,d1], bf16x3 MFMA over s-chunks,
// fp32 atomic accumulate. grid (8 s-chunks, 32 bh), 64 threads (1 wave).
// ---------------------------------------------------------------------------
__global__ __launch_bounds__(64) void mt_kernel(
    const unsigned short* __restrict__ KtH, const unsigned short* __restrict__ KtL,
    const unsigned short* __restrict__ VtH, const unsigned short* __restrict__ VtL,
    float* __restrict__ Mt)
{
    const int bh = blockIdx.y;
    const int s0 = blockIdx.x * 256;
    const int lane = threadIdx.x, quad = lane >> 4, lrow = lane & 15;
    const size_t headoff = (size_t)bh * 64 * 2048;

    f32x4 acc[4][4] = {};
    for (int ks = 0; ks < 8; ++ks) {
        const int kk = s0 + ks * 32 + quad * 8;
        bf16x8 va_h[4], va_l[4], kb_h[4], kb_l[4];
        #pragma unroll
        for (int t = 0; t < 4; ++t) {
            size_t o = headoff + (size_t)(t * 16 + lrow) * 2048 + kk;
            va_h[t] = *(const bf16x8*)&VtH[o];
            va_l[t] = *(const bf16x8*)&VtL[o];
            kb_h[t] = *(const bf16x8*)&KtH[o];
            kb_l[t] = *(const bf16x8*)&KtL[o];
        }
        #pragma unroll
        for (int it = 0; it < 4; ++it)
            #pragma unroll
            for (int jt = 0; jt < 4; ++jt) {
                acc[it][jt] = __builtin_amdgcn_mfma_f32_16x16x32_bf16(va_h[it], kb_h[jt], acc[it][jt], 0, 0, 0);
                acc[it][jt] = __builtin_amdgcn_mfma_f32_16x16x32_bf16(va_h[it], kb_l[jt], acc[it][jt], 0, 0, 0);
                acc[it][jt] = __builtin_amdgcn_mfma_f32_16x16x32_bf16(va_l[it], kb_h[jt], acc[it][jt], 0, 0, 0);
            }
    }
    #pragma unroll
    for (int it = 0; it < 4; ++it)
        #pragma unroll
        for (int jt = 0; jt < 4; ++jt)
            #pragma unroll
            for (int r = 0; r < 4; ++r)
                atomicAdd(&Mt[((size_t)bh * 64 + it * 16 + quad * 4 + r) * 64 + jt * 16 + lrow],
                          acc[it][jt][r]);
}

// ---------------------------------------------------------------------------
// Y[t][d2] = (sum_d1 Qrot[t][d1] * Mt[d2][d1]) / den[bh][t], bf16 hi/lo out.
// grid (32 t-tiles, 32 bh), 64 threads (1 wave).
// ---------------------------------------------------------------------------
__global__ __launch_bounds__(64) void y_kernel(
    const unsigned short* __restrict__ Qh, const unsigned short* __restrict__ Ql,
    const float* __restrict__ Mt, const float* __restrict__ den,
    unsigned short* __restrict__ Yh, unsigned short* __restrict__ Yl)
{
    const int bh = blockIdx.y, b = bh >> 4, h = bh & 15;
    const int t0 = blockIdx.x * 64;
    const int lane = threadIdx.x, quad = lane >> 4, lrow = lane & 15;

    // B-frags: Mt rows (d2), contiguous in d1; fp32 -> bf16 hi/lo in regs
    bf16x8 mbh[4][2], mbl[4][2];
    #pragma unroll
    for (int jt = 0; jt < 4; ++jt)
        #pragma unroll
        for (int kk = 0; kk < 2; ++kk) {
            const float* mp = &Mt[((size_t)bh * 64 + jt * 16 + lrow) * 64 + kk * 32 + quad * 8];
            #pragma unroll
            for (int e = 0; e < 8; ++e) {
                float x = mp[e];
                unsigned short hh = bf16_rne(x);
                mbh[jt][kk][e] = (short)hh;
                mbl[jt][kk][e] = (short)bf16_rne(x - bf16_to_f(hh));
            }
        }

    f32x4 acc[4][4] = {};
    #pragma unroll
    for (int kk = 0; kk < 2; ++kk)
        #pragma unroll
        for (int it = 0; it < 4; ++it) {
            size_t ao = ((size_t)(b * T_SEQ + t0 + it * 16 + lrow)) * C_EMB
                      + h * 64 + kk * 32 + quad * 8;
            bf16x8 a_h = *(const bf16x8*)&Qh[ao];
            bf16x8 a_l = *(const bf16x8*)&Ql[ao];
            #pragma unroll
            for (int jt = 0; jt < 4; ++jt) {
                acc[it][jt] = __builtin_amdgcn_mfma_f32_16x16x32_bf16(a_h, mbh[jt][kk], acc[it][jt], 0, 0, 0);
                acc[it][jt] = __builtin_amdgcn_mfma_f32_16x16x32_bf16(a_h, mbl[jt][kk], acc[it][jt], 0, 0, 0);
                acc[it][jt] = __builtin_amdgcn_mfma_f32_16x16x32_bf16(a_l, mbh[jt][kk], acc[it][jt], 0, 0, 0);
            }
        }

    #pragma unroll
    for (int it = 0; it < 4; ++it) {
        float4 d4 = *(const float4*)&den[(size_t)bh * T_SEQ + t0 + it * 16 + quad * 4];
        const float* dp = &d4.x;
        #pragma unroll
        for (int jt = 0; jt < 4; ++jt)
            #pragma unroll
            for (int r = 0; r < 4; ++r) {
                float v = acc[it][jt][r] / dp[r];
                size_t o = ((size_t)(b * T_SEQ + t0 + it * 16 + quad * 4 + r)) * C_EMB
                         + h * 64 + jt * 16 + lrow;
                unsigned short hh = bf16_rne(v);
                Yh[o] = hh;
                Yl[o] = bf16_rne(v - bf16_to_f(hh));
            }
    }
}

// ---------------------------------------------------------------------------
// Output projection GEMM: out = Y @ proj_w + proj_b (fp32 out). N = 1024.
// ---------------------------------------------------------------------------
__global__ __launch_bounds__(256) void gemm_out(
    const unsigned short* __restrict__ Ah, const unsigned short* __restrict__ Al,
    const unsigned short* __restrict__ Bth, const unsigned short* __restrict__ Btl,
    const float* __restrict__ bias, float* __restrict__ out)
{
    __shared__ unsigned short lds[16384];
    const int m0 = blockIdx.y * 128, n0 = blockIdx.x * 128;
    f32x4 acc[4][4] = {};
    gemm_main_loop(Ah, Al, Bth, Btl, lds, m0, n0, acc);

    const int tid = threadIdx.x;
    const int w = tid >> 6, lane = tid & 63;
    const int wr = w >> 1, wc = w & 1;
    const int quad = lane >> 4, lrow = lane & 15;

    #pragma unroll
    for (int jt = 0; jt < 4; ++jt) {
        int gc = n0 + wc * 64 + jt * 16 + lrow;
        float bb = bias[gc];
        #pragma unroll
        for (int it = 0; it < 4; ++it) {
            int grb = m0 + wr * 64 + it * 16 + quad * 4;
            #pragma unroll
            for (int r = 0; r < 4; ++r)
                out[(size_t)(grb + r) * C_EMB + gc] = acc[it][jt][r] + bb;
        }
    }
}

// ---------------------------------------------------------------------------
extern "C" void kernel_launch(void* const* d_in, const int* in_sizes, int n_in,
                              void* d_out, int out_size, void* d_ws, size_t ws_size,
                              hipStream_t stream)
{
    const float* x      = (const float*)d_in[0];
    const float* memory = (const float*)d_in[1];
    const float* q_w    = (const float*)d_in[2];
    const float* q_b    = (const float*)d_in[3];
    const float* kv_w   = (const float*)d_in[4];
    const float* kv_b   = (const float*)d_in[5];
    const float* proj_w = (const float*)d_in[6];
    const float* proj_b = (const float*)d_in[7];

    if (ws_size < WS_FLOATS * sizeof(float)) return;

    float* ws = (float*)d_ws;
    unsigned short* xh    = (unsigned short*)(ws + OFF_XH);
    unsigned short* xl    = (unsigned short*)(ws + OFF_XL);
    unsigned short* mh    = (unsigned short*)(ws + OFF_MEMH);
    unsigned short* ml    = (unsigned short*)(ws + OFF_MEML);
    unsigned short* qwh   = (unsigned short*)(ws + OFF_QWH);
    unsigned short* qwl   = (unsigned short*)(ws + OFF_QWL);
    unsigned short* kvwh  = (unsigned short*)(ws + OFF_KVWH);
    unsigned short* kvwl  = (unsigned short*)(ws + OFF_KVWL);
    unsigned short* pwh   = (unsigned short*)(ws + OFF_PWH);
    unsigned short* pwl   = (unsigned short*)(ws + OFF_PWL);
    unsigned short* KtH   = (unsigned short*)(ws + OFF_KTH);
    unsigned short* KtL   = (unsigned short*)(ws + OFF_KTL);
    unsigned short* VtH   = (unsigned short*)(ws + OFF_VTH);
    unsigned short* VtL   = (unsigned short*)(ws + OFF_VTL);
    unsigned short* Qroth = mh;   // alias: mem splits dead after KV GEMM
    unsigned short* Qrotl = ml;
    unsigned short* Yh    = xh;   // alias: x splits dead after Q GEMM
    unsigned short* Yl    = xl;
    float*  Ksum = ws + OFF_KSUM;
    float*  Mm   = ws + OFF_MT;
    float*  den  = ws + OFF_DEN;
    float2* tab  = (float2*)(ws + OFF_TAB);

    // Zero Ksum + Mt (contiguous)
    hipMemsetAsync(Ksum, 0, (2048 + 131072) * sizeof(float), stream);
    rope_table_kernel<<<256, 256, 0, stream>>>(tab);

    split_kernel<<<4096, 256, 0, stream>>>((const float4*)x, (ushort4*)xh, (ushort4*)xl, 1048576);
    split_kernel<<<4096, 256, 0, stream>>>((const float4*)memory, (ushort4*)mh, (ushort4*)ml, 1048576);
    split_transpose_kernel<<<dim3(32, 32), 256, 0, stream>>>(q_w, qwh, qwl, 1024, 1024);
    split_transpose_kernel<<<dim3(64, 32), 256, 0, stream>>>(kv_w, kvwh, kvwl, 1024, 2048);
    split_transpose_kernel<<<dim3(32, 32), 256, 0, stream>>>(proj_w, pwh, pwl, 1024, 1024);

    // KV GEMM (+elu on K, Ksum, RoPE, transposed bf16 hi/lo K/V)
    gemm_kv<<<dim3(16, 32), 256, 0, stream>>>(mh, ml, kvwh, kvwl, kv_b, tab,
                                              Ksum, KtH, KtL, VtH, VtL);
    // Mt = V^T Krot per head
    mt_kernel<<<dim3(8, 32), 64, 0, stream>>>(KtH, KtL, VtH, VtL, Mm);
    // Q GEMM (+elu, denom, RoPE, bf16 hi/lo Qrot)
    gemm_q<<<dim3(8, 32), 256, 0, stream>>>(xh, xl, qwh, qwl, q_b, tab,
                                            Ksum, den, Qroth, Qrotl);
    // Y = (Qrot @ Mt^T)/den -> bf16 hi/lo
    y_kernel<<<dim3(32, 32), 64, 0, stream>>>(Qroth, Qrotl, Mm, den, Yh, Yl);
    // out = Y @ proj_w + proj_b
    gemm_out<<<dim3(8, 32), 256, 0, stream>>>(Yh, Yl, pwh, pwl, proj_b, (float*)d_out);
}

// Round 4
// 271.073 us; speedup vs baseline: 2.3246x; 1.1046x over previous
//
#include <hip/hip_runtime.h>
#include <cstddef>
#include <cstdint>

// Problem constants
#define B_SZ  2
#define T_SEQ 2048
#define S_SEQ 2048
#define C_EMB 1024
#define NH    16
#define HD    64
#define KDIM  1024   // inner dim of the three big GEMMs

typedef __attribute__((ext_vector_type(8))) short bf16x8;
typedef __attribute__((ext_vector_type(4))) float f32x4;

// ---------------------------------------------------------------------------
// Workspace layout (float units).
// ---------------------------------------------------------------------------
#define OFF_XH    ((size_t)0)           // [4096,1024] ushort
#define OFF_XL    ((size_t)2097152)
#define OFF_MEMH  ((size_t)4194304)     // [4096,1024] ushort
#define OFF_MEML  ((size_t)6291456)
#define OFF_QWH   ((size_t)8388608)     // [1024,1024] ushort (transposed [N,K])
#define OFF_QWL   ((size_t)8912896)
#define OFF_KVWH  ((size_t)9437184)     // [2048,1024] ushort
#define OFF_KVWL  ((size_t)10485760)
#define OFF_PWH   ((size_t)11534336)    // [1024,1024] ushort
#define OFF_PWL   ((size_t)12058624)
#define OFF_KSUM  ((size_t)12582912)    // [2,1024]
#define OFF_MT    ((size_t)12584960)    // [32,64,64] fp32  Mt[d2][d1]
#define OFF_TAB   ((size_t)12716032)    // [2048,32] float2
#define OFF_YH    ((size_t)12847104)    // [4096,1024] ushort
#define OFF_YL    ((size_t)14944256)
#define WS_FLOATS ((size_t)17041408)    // ~68.2 MB

__device__ __forceinline__ float elu1(float v) {
    return v > 0.0f ? v + 1.0f : __expf(v);
}
__device__ __forceinline__ unsigned short bf16_rne(float x) {
    union { float f; unsigned int u; } v; v.f = x;
    unsigned int u = v.u;
    return (unsigned short)((u + 0x7FFFu + ((u >> 16) & 1u)) >> 16);
}
__device__ __forceinline__ float bf16_to_f(unsigned short h) {
    union { unsigned int u; float f; } v; v.u = ((unsigned int)h) << 16;
    return v.f;
}

// ---------------------------------------------------------------------------
// Elementwise split: fp32 -> hi(bf16) + lo(bf16)
// ---------------------------------------------------------------------------
__global__ __launch_bounds__(256) void split_kernel(
    const float4* __restrict__ in, ushort4* __restrict__ hi,
    ushort4* __restrict__ lo, int n4)
{
    int i = blockIdx.x * 256 + threadIdx.x;
    if (i >= n4) return;
    float4 v = in[i];
    ushort4 h, l;
    h.x = bf16_rne(v.x); l.x = bf16_rne(v.x - bf16_to_f(h.x));
    h.y = bf16_rne(v.y); l.y = bf16_rne(v.y - bf16_to_f(h.y));
    h.z = bf16_rne(v.z); l.z = bf16_rne(v.z - bf16_to_f(h.z));
    h.w = bf16_rne(v.w); l.w = bf16_rne(v.w - bf16_to_f(h.w));
    hi[i] = h; lo[i] = l;
}

// ---------------------------------------------------------------------------
// Weight split + transpose: W[K,N] fp32 -> Wt_hi/Wt_lo[N,K] bf16
// ---------------------------------------------------------------------------
__global__ __launch_bounds__(256) void split_transpose_kernel(
    const float* __restrict__ W, unsigned short* __restrict__ Wth,
    unsigned short* __restrict__ Wtl, int K, int N)
{
    __shared__ float tile[32][33];
    const int k0 = blockIdx.y * 32, n0 = blockIdx.x * 32;
    const int tx = threadIdx.x & 31, ty = threadIdx.x >> 5;
    #pragma unroll
    for (int j = 0; j < 4; ++j)
        tile[ty + j * 8][tx] = W[(size_t)(k0 + ty + j * 8) * N + n0 + tx];
    __syncthreads();
    #pragma unroll
    for (int j = 0; j < 4; ++j) {
        float x = tile[tx][ty + j * 8];
        unsigned short h = bf16_rne(x);
        unsigned short l = bf16_rne(x - bf16_to_f(h));
        size_t o = (size_t)(n0 + ty + j * 8) * K + k0 + tx;
        Wth[o] = h; Wtl[o] = l;
    }
}

// ---------------------------------------------------------------------------
// RoPE cos/sin table
// ---------------------------------------------------------------------------
__global__ __launch_bounds__(256) void rope_table_kernel(float2* __restrict__ tab) {
    int idx = blockIdx.x * 256 + threadIdx.x;   // pos*32 + i
    int pos = idx >> 5, i = idx & 31;
    double invf = exp(-(double)i * (9.210340371976184 / 32.0));  // 10000^(-i/32)
    float arg = (float)((double)pos * invf);
    float sn, cs;
    sincosf(arg, &sn, &cs);
    tab[idx] = make_float2(cs, sn);
}

// ---------------------------------------------------------------------------
// Generic bf16x3 MFMA main loop (A rows m0.., B^T rows n0..). Fills acc[4][4].
// ---------------------------------------------------------------------------
__device__ __forceinline__ void gemm_main_loop(
    const unsigned short* __restrict__ Ah, const unsigned short* __restrict__ Al,
    const unsigned short* __restrict__ Bth, const unsigned short* __restrict__ Btl,
    unsigned short* lds, int m0, int n0, f32x4 acc[4][4])
{
    const int tid = threadIdx.x;
    const int w = tid >> 6, lane = tid & 63;
    const int wr = w >> 1, wc = w & 1;
    const int quad = lane >> 4, lrow = lane & 15;

    const unsigned short* src = (w == 0) ? Ah : (w == 1) ? Al : (w == 2) ? Bth : Btl;
    const int rbase = (w < 2) ? m0 : n0;
    const int srow = lane >> 2;
    const int scol = (lane & 3) * 8;
    const unsigned short* gsrc = src + (size_t)(rbase + srow) * KDIM + scol;
    unsigned short* lbase = &lds[w * 4096];

    const unsigned short* As_h = lds;
    const unsigned short* As_l = lds + 4096;
    const unsigned short* Bs_h = lds + 8192;
    const unsigned short* Bs_l = lds + 12288;

    for (int k0 = 0; k0 < KDIM; k0 += 32) {
        #pragma unroll
        for (int i = 0; i < 8; ++i) {
            __builtin_amdgcn_global_load_lds(
                (const __attribute__((address_space(1))) unsigned int*)(gsrc + (size_t)i * 16 * KDIM + k0),
                (__attribute__((address_space(3))) unsigned int*)(lbase + i * 512),
                16, 0, 0);
        }
        __syncthreads();

        bf16x8 bh[4], bl[4];
        #pragma unroll
        for (int jt = 0; jt < 4; ++jt) {
            int nl = wc * 64 + jt * 16 + lrow;
            bh[jt] = *(const bf16x8*)&Bs_h[nl * 32 + quad * 8];
            bl[jt] = *(const bf16x8*)&Bs_l[nl * 32 + quad * 8];
        }
        #pragma unroll
        for (int it = 0; it < 4; ++it) {
            int ml = wr * 64 + it * 16 + lrow;
            bf16x8 ah = *(const bf16x8*)&As_h[ml * 32 + quad * 8];
            bf16x8 al = *(const bf16x8*)&As_l[ml * 32 + quad * 8];
            #pragma unroll
            for (int jt = 0; jt < 4; ++jt) {
                acc[it][jt] = __builtin_amdgcn_mfma_f32_16x16x32_bf16(ah, bh[jt], acc[it][jt], 0, 0, 0);
                acc[it][jt] = __builtin_amdgcn_mfma_f32_16x16x32_bf16(ah, bl[jt], acc[it][jt], 0, 0, 0);
                acc[it][jt] = __builtin_amdgcn_mfma_f32_16x16x32_bf16(al, bh[jt], acc[it][jt], 0, 0, 0);
            }
        }
        __syncthreads();
    }
}

// ---------------------------------------------------------------------------
// KV GEMM, head-paired columns: block (h, mtile) computes K-slice (cols
// h*64..) and V-slice (cols 1024+h*64..) for 128 memory rows. Epilogue:
// bias, elu+1(K), Ksum atomics, RoPE in registers, LDS transpose ->
// Mt[d2][d1] += V^T Krot via MFMA + atomicAdd. No K/V global output.
// grid (16 heads, 32 mtiles).
// ---------------------------------------------------------------------------
__global__ __launch_bounds__(256) void gemm_kv(
    const unsigned short* __restrict__ Ah, const unsigned short* __restrict__ Al,
    const unsigned short* __restrict__ Bth, const unsigned short* __restrict__ Btl,
    const float* __restrict__ bias, const float2* __restrict__ tab,
    float* __restrict__ Ksum, float* __restrict__ Mt)
{
    // main loop uses [0,16384); epilogue reuses all 34816 (KH/KL/VH/VL, 64x136)
    __shared__ unsigned short smem[34816];
    const int tid = threadIdx.x;
    const int w = tid >> 6, lane = tid & 63;
    const int wr = w >> 1, wc = w & 1;
    const int quad = lane >> 4, lrow = lane & 15;
    const int h  = blockIdx.x;
    const int m0 = blockIdx.y * 128;
    const int b  = m0 >> 11;
    const int tbase = (m0 & 2047) + wr * 64;

    // ---- main loop (B rows remapped: local col>=64 -> +960) ----
    {
        const unsigned short* src = (w == 0) ? Ah : (w == 1) ? Al : (w == 2) ? Bth : Btl;
        const int srow = lane >> 2, scol = (lane & 3) * 8;
        const size_t rowbase = (w < 2) ? (size_t)(m0 + srow) : (size_t)(h * 64 + srow);
        const unsigned short* gsrc = src + rowbase * KDIM + scol;
        const size_t vskip = (w >= 2) ? (size_t)960 * KDIM : 0;
        unsigned short* lbase = &smem[w * 4096];
        const unsigned short* As_h = smem;
        const unsigned short* As_l = smem + 4096;
        const unsigned short* Bs_h = smem + 8192;
        const unsigned short* Bs_l = smem + 12288;

        f32x4 acc[4][4] = {};
        for (int k0 = 0; k0 < KDIM; k0 += 32) {
            #pragma unroll
            for (int i = 0; i < 8; ++i) {
                size_t goff = (size_t)i * 16 * KDIM + k0 + ((i >= 4) ? vskip : 0);
                __builtin_amdgcn_global_load_lds(
                    (const __attribute__((address_space(1))) unsigned int*)(gsrc + goff),
                    (__attribute__((address_space(3))) unsigned int*)(lbase + i * 512),
                    16, 0, 0);
            }
            __syncthreads();
            bf16x8 bh[4], bl[4];
            #pragma unroll
            for (int jt = 0; jt < 4; ++jt) {
                int nl = wc * 64 + jt * 16 + lrow;
                bh[jt] = *(const bf16x8*)&Bs_h[nl * 32 + quad * 8];
                bl[jt] = *(const bf16x8*)&Bs_l[nl * 32 + quad * 8];
            }
            #pragma unroll
            for (int it = 0; it < 4; ++it) {
                int ml = wr * 64 + it * 16 + lrow;
                bf16x8 ah = *(const bf16x8*)&As_h[ml * 32 + quad * 8];
                bf16x8 al = *(const bf16x8*)&As_l[ml * 32 + quad * 8];
                #pragma unroll
                for (int jt = 0; jt < 4; ++jt) {
                    acc[it][jt] = __builtin_amdgcn_mfma_f32_16x16x32_bf16(ah, bh[jt], acc[it][jt], 0, 0, 0);
                    acc[it][jt] = __builtin_amdgcn_mfma_f32_16x16x32_bf16(ah, bl[jt], acc[it][jt], 0, 0, 0);
                    acc[it][jt] = __builtin_amdgcn_mfma_f32_16x16x32_bf16(al, bh[jt], acc[it][jt], 0, 0, 0);
                }
            }
            __syncthreads();
        }

        // ---- epilogue part 1: bias / elu / Ksum / rope, then LDS transpose ----
        const bool isK = (wc == 0);
        const int colg = (isK ? 0 : C_EMB) + h * 64;
        float bb[4];
        #pragma unroll
        for (int jt = 0; jt < 4; ++jt) bb[jt] = bias[colg + jt * 16 + lrow];
        #pragma unroll
        for (int it = 0; it < 4; ++it)
            #pragma unroll
            for (int jt = 0; jt < 4; ++jt)
                #pragma unroll
                for (int r = 0; r < 4; ++r) {
                    float v = acc[it][jt][r] + bb[jt];
                    acc[it][jt][r] = isK ? elu1(v) : v;
                }

        if (isK) {
            #pragma unroll
            for (int jt = 0; jt < 4; ++jt) {
                float p = 0.0f;
                #pragma unroll
                for (int it = 0; it < 4; ++it)
                    #pragma unroll
                    for (int r = 0; r < 4; ++r) p += acc[it][jt][r];
                p += __shfl_xor(p, 16);
                p += __shfl_xor(p, 32);
                if (quad == 0)
                    atomicAdd(&Ksum[b * C_EMB + h * 64 + jt * 16 + lrow], p);
            }
            #pragma unroll
            for (int it = 0; it < 4; ++it)
                #pragma unroll
                for (int r = 0; r < 4; ++r) {
                    int s = tbase + it * 16 + quad * 4 + r;
                    float2 c0 = tab[s * 32 + lrow];
                    float2 c1 = tab[s * 32 + 16 + lrow];
                    float a0 = acc[it][0][r], a1 = acc[it][1][r];
                    float a2 = acc[it][2][r], a3 = acc[it][3][r];
                    acc[it][0][r] = a0 * c0.x - a2 * c0.y;
                    acc[it][2][r] = a2 * c0.x + a0 * c0.y;
                    acc[it][1][r] = a1 * c1.x - a3 * c1.y;
                    acc[it][3][r] = a3 * c1.x + a1 * c1.y;
                }
        }

        // transposed LDS: K_hi[64][136] @0, K_lo @8704, V_hi @17408, V_lo @26112
        unsigned short* Hd = smem + (isK ? 0 : 17408);
        unsigned short* Ld = Hd + 8704;
        #pragma unroll
        for (int jt = 0; jt < 4; ++jt) {
            int d = jt * 16 + lrow;
            #pragma unroll
            for (int it = 0; it < 4; ++it) {
                int t0loc = wr * 64 + it * 16 + quad * 4;
                ushort4 h4, l4;
                float v0 = acc[it][jt][0], v1 = acc[it][jt][1];
                float v2 = acc[it][jt][2], v3 = acc[it][jt][3];
                h4.x = bf16_rne(v0); l4.x = bf16_rne(v0 - bf16_to_f(h4.x));
                h4.y = bf16_rne(v1); l4.y = bf16_rne(v1 - bf16_to_f(h4.y));
                h4.z = bf16_rne(v2); l4.z = bf16_rne(v2 - bf16_to_f(h4.z));
                h4.w = bf16_rne(v3); l4.w = bf16_rne(v3 - bf16_to_f(h4.w));
                *(ushort4*)&Hd[d * 136 + t0loc] = h4;
                *(ushort4*)&Ld[d * 136 + t0loc] = l4;
            }
        }
    }
    __syncthreads();

    // ---- epilogue part 2: Mt[d2][d1] += sum_t V[t][d2]*Krot[t][d1] ----
    {
        const unsigned short* KH = smem;
        const unsigned short* KL = smem + 8704;
        const unsigned short* VH = smem + 17408;
        const unsigned short* VL = smem + 26112;
        const int mrow = w * 16 + lrow;          // d2 strip per wave
        f32x4 macc[4] = {};
        #pragma unroll
        for (int ks = 0; ks < 4; ++ks) {
            int kof = ks * 32 + quad * 8;
            bf16x8 vah = *(const bf16x8*)&VH[mrow * 136 + kof];
            bf16x8 val = *(const bf16x8*)&VL[mrow * 136 + kof];
            #pragma unroll
            for (int jt = 0; jt < 4; ++jt) {
                int nrow = jt * 16 + lrow;       // d1
                bf16x8 kbh = *(const bf16x8*)&KH[nrow * 136 + kof];
                bf16x8 kbl = *(const bf16x8*)&KL[nrow * 136 + kof];
                macc[jt] = __builtin_amdgcn_mfma_f32_16x16x32_bf16(vah, kbh, macc[jt], 0, 0, 0);
                macc[jt] = __builtin_amdgcn_mfma_f32_16x16x32_bf16(vah, kbl, macc[jt], 0, 0, 0);
                macc[jt] = __builtin_amdgcn_mfma_f32_16x16x32_bf16(val, kbh, macc[jt], 0, 0, 0);
            }
        }
        const int bh = b * NH + h;
        #pragma unroll
        for (int jt = 0; jt < 4; ++jt)
            #pragma unroll
            for (int r = 0; r < 4; ++r)
                atomicAdd(&Mt[((size_t)bh * 64 + w * 16 + quad * 4 + r) * 64 + jt * 16 + lrow],
                          macc[jt][r]);
    }
}

// ---------------------------------------------------------------------------
// Q GEMM + full attention epilogue: bias, elu+1, den in registers, RoPE,
// Qrot -> per-wave LDS, Y = (Qrot @ Mt^T)/den via MFMA, bf16 hi/lo stores.
// Each wave's 64 cols = one complete head. grid (8, 32).
// ---------------------------------------------------------------------------
__global__ __launch_bounds__(256) void gemm_q(
    const unsigned short* __restrict__ Ah, const unsigned short* __restrict__ Al,
    const unsigned short* __restrict__ Bth, const unsigned short* __restrict__ Btl,
    const float* __restrict__ bias, const float2* __restrict__ tab,
    const float* __restrict__ Ksum, const float* __restrict__ Mt,
    unsigned short* __restrict__ Yh, unsigned short* __restrict__ Yl)
{
    // main loop uses [0,16384); epilogue per-wave Qrot hi/lo [64][72] @ w*9216
    __shared__ unsigned short smem[36864];
    const int m0 = blockIdx.y * 128, n0 = blockIdx.x * 128;
    f32x4 acc[4][4] = {};
    gemm_main_loop(Ah, Al, Bth, Btl, smem, m0, n0, acc);

    const int tid = threadIdx.x;
    const int w = tid >> 6, lane = tid & 63;
    const int wr = w >> 1, wc = w & 1;
    const int quad = lane >> 4, lrow = lane & 15;
    const int h = blockIdx.x * 2 + wc;
    const int b = m0 >> 11;
    const int tbase = (m0 & 2047) + wr * 64;
    const int bh = b * NH + h;

    float bb[4];
    #pragma unroll
    for (int jt = 0; jt < 4; ++jt) bb[jt] = bias[h * 64 + jt * 16 + lrow];
    #pragma unroll
    for (int it = 0; it < 4; ++it)
        #pragma unroll
        for (int jt = 0; jt < 4; ++jt)
            #pragma unroll
            for (int r = 0; r < 4; ++r)
                acc[it][jt][r] = elu1(acc[it][jt][r] + bb[jt]);

    // den (pre-rope), kept in registers (uniform over lrow after reduction)
    float ks[4], den_reg[4][4];
    #pragma unroll
    for (int jt = 0; jt < 4; ++jt) ks[jt] = Ksum[b * C_EMB + h * 64 + jt * 16 + lrow];
    #pragma unroll
    for (int it = 0; it < 4; ++it)
        #pragma unroll
        for (int r = 0; r < 4; ++r) {
            float p = acc[it][0][r] * ks[0] + acc[it][1][r] * ks[1]
                    + acc[it][2][r] * ks[2] + acc[it][3][r] * ks[3];
            p += __shfl_xor(p, 1);
            p += __shfl_xor(p, 2);
            p += __shfl_xor(p, 4);
            p += __shfl_xor(p, 8);
            den_reg[it][r] = p;
        }

    // RoPE in registers
    #pragma unroll
    for (int it = 0; it < 4; ++it)
        #pragma unroll
        for (int r = 0; r < 4; ++r) {
            int s = tbase + it * 16 + quad * 4 + r;
            float2 c0 = tab[s * 32 + lrow];
            float2 c1 = tab[s * 32 + 16 + lrow];
            float a0 = acc[it][0][r], a1 = acc[it][1][r];
            float a2 = acc[it][2][r], a3 = acc[it][3][r];
            acc[it][0][r] = a0 * c0.x - a2 * c0.y;
            acc[it][2][r] = a2 * c0.x + a0 * c0.y;
            acc[it][1][r] = a1 * c1.x - a3 * c1.y;
            acc[it][3][r] = a3 * c1.x + a1 * c1.y;
        }

    // Qrot -> per-wave LDS (row-major [t][d], stride 72)
    unsigned short* QH = smem + w * 9216;
    unsigned short* QL = QH + 4608;
    #pragma unroll
    for (int it = 0; it < 4; ++it)
        #pragma unroll
        for (int jt = 0; jt < 4; ++jt)
            #pragma unroll
            for (int r = 0; r < 4; ++r) {
                int tloc = it * 16 + quad * 4 + r;
                int d = jt * 16 + lrow;
                float v = acc[it][jt][r];
                unsigned short hh = bf16_rne(v);
                QH[tloc * 72 + d] = hh;
                QL[tloc * 72 + d] = bf16_rne(v - bf16_to_f(hh));
            }
    __syncthreads();

    // Y = (Qrot @ Mt^T) / den
    f32x4 acc2[4][4] = {};
    #pragma unroll
    for (int kc = 0; kc < 2; ++kc) {
        bf16x8 mbh[4], mbl[4];
        #pragma unroll
        for (int jt2 = 0; jt2 < 4; ++jt2) {
            const float* mp = &Mt[((size_t)bh * 64 + jt2 * 16 + lrow) * 64 + kc * 32 + quad * 8];
            #pragma unroll
            for (int e = 0; e < 8; ++e) {
                float x = mp[e];
                unsigned short hh = bf16_rne(x);
                mbh[jt2][e] = (short)hh;
                mbl[jt2][e] = (short)bf16_rne(x - bf16_to_f(hh));
            }
        }
        #pragma unroll
        for (int it2 = 0; it2 < 4; ++it2) {
            int ro = (it2 * 16 + lrow) * 72 + kc * 32 + quad * 8;
            bf16x8 qh = *(const bf16x8*)&QH[ro];
            bf16x8 ql = *(const bf16x8*)&QL[ro];
            #pragma unroll
            for (int jt2 = 0; jt2 < 4; ++jt2) {
                acc2[it2][jt2] = __builtin_amdgcn_mfma_f32_16x16x32_bf16(qh, mbh[jt2], acc2[it2][jt2], 0, 0, 0);
                acc2[it2][jt2] = __builtin_amdgcn_mfma_f32_16x16x32_bf16(qh, mbl[jt2], acc2[it2][jt2], 0, 0, 0);
                acc2[it2][jt2] = __builtin_amdgcn_mfma_f32_16x16x32_bf16(ql, mbh[jt2], acc2[it2][jt2], 0, 0, 0);
            }
        }
    }

    // divide + bf16 hi/lo store
    #pragma unroll
    for (int it2 = 0; it2 < 4; ++it2)
        #pragma unroll
        for (int jt2 = 0; jt2 < 4; ++jt2)
            #pragma unroll
            for (int r = 0; r < 4; ++r) {
                float v = acc2[it2][jt2][r] / den_reg[it2][r];
                size_t o = ((size_t)(m0 + wr * 64 + it2 * 16 + quad * 4 + r)) * C_EMB
                         + h * 64 + jt2 * 16 + lrow;
                unsigned short hh = bf16_rne(v);
                Yh[o] = hh;
                Yl[o] = bf16_rne(v - bf16_to_f(hh));
            }
}

// ---------------------------------------------------------------------------
// Output projection GEMM: out = Y @ proj_w + proj_b (fp32 out). N = 1024.
// ---------------------------------------------------------------------------
__global__ __launch_bounds__(256) void gemm_out(
    const unsigned short* __restrict__ Ah, const unsigned short* __restrict__ Al,
    const unsigned short* __restrict__ Bth, const unsigned short* __restrict__ Btl,
    const float* __restrict__ bias, float* __restrict__ out)
{
    __shared__ unsigned short lds[16384];
    const int m0 = blockIdx.y * 128, n0 = blockIdx.x * 128;
    f32x4 acc[4][4] = {};
    gemm_main_loop(Ah, Al, Bth, Btl, lds, m0, n0, acc);

    const int tid = threadIdx.x;
    const int w = tid >> 6, lane = tid & 63;
    const int wr = w >> 1, wc = w & 1;
    const int quad = lane >> 4, lrow = lane & 15;

    #pragma unroll
    for (int jt = 0; jt < 4; ++jt) {
        int gc = n0 + wc * 64 + jt * 16 + lrow;
        float bb = bias[gc];
        #pragma unroll
        for (int it = 0; it < 4; ++it) {
            int grb = m0 + wr * 64 + it * 16 + quad * 4;
            #pragma unroll
            for (int r = 0; r < 4; ++r)
                out[(size_t)(grb + r) * C_EMB + gc] = acc[it][jt][r] + bb;
        }
    }
}

// ---------------------------------------------------------------------------
extern "C" void kernel_launch(void* const* d_in, const int* in_sizes, int n_in,
                              void* d_out, int out_size, void* d_ws, size_t ws_size,
                              hipStream_t stream)
{
    const float* x      = (const float*)d_in[0];
    const float* memory = (const float*)d_in[1];
    const float* q_w    = (const float*)d_in[2];
    const float* q_b    = (const float*)d_in[3];
    const float* kv_w   = (const float*)d_in[4];
    const float* kv_b   = (const float*)d_in[5];
    const float* proj_w = (const float*)d_in[6];
    const float* proj_b = (const float*)d_in[7];

    if (ws_size < WS_FLOATS * sizeof(float)) return;

    float* ws = (float*)d_ws;
    unsigned short* xh   = (unsigned short*)(ws + OFF_XH);
    unsigned short* xl   = (unsigned short*)(ws + OFF_XL);
    unsigned short* mh   = (unsigned short*)(ws + OFF_MEMH);
    unsigned short* ml   = (unsigned short*)(ws + OFF_MEML);
    unsigned short* qwh  = (unsigned short*)(ws + OFF_QWH);
    unsigned short* qwl  = (unsigned short*)(ws + OFF_QWL);
    unsigned short* kvwh = (unsigned short*)(ws + OFF_KVWH);
    unsigned short* kvwl = (unsigned short*)(ws + OFF_KVWL);
    unsigned short* pwh  = (unsigned short*)(ws + OFF_PWH);
    unsigned short* pwl  = (unsigned short*)(ws + OFF_PWL);
    unsigned short* Yh   = (unsigned short*)(ws + OFF_YH);
    unsigned short* Yl   = (unsigned short*)(ws + OFF_YL);
    float*  Ksum = ws + OFF_KSUM;
    float*  Mm   = ws + OFF_MT;
    float2* tab  = (float2*)(ws + OFF_TAB);

    // Zero Ksum + Mt (contiguous)
    hipMemsetAsync(Ksum, 0, (2048 + 131072) * sizeof(float), stream);
    rope_table_kernel<<<256, 256, 0, stream>>>(tab);

    split_kernel<<<4096, 256, 0, stream>>>((const float4*)x, (ushort4*)xh, (ushort4*)xl, 1048576);
    split_kernel<<<4096, 256, 0, stream>>>((const float4*)memory, (ushort4*)mh, (ushort4*)ml, 1048576);
    split_transpose_kernel<<<dim3(32, 32), 256, 0, stream>>>(q_w, qwh, qwl, 1024, 1024);
    split_transpose_kernel<<<dim3(64, 32), 256, 0, stream>>>(kv_w, kvwh, kvwl, 1024, 2048);
    split_transpose_kernel<<<dim3(32, 32), 256, 0, stream>>>(proj_w, pwh, pwl, 1024, 1024);

    // KV GEMM (+elu/Ksum/rope + fused Mt accumulate). No K/V global output.
    gemm_kv<<<dim3(16, 32), 256, 0, stream>>>(mh, ml, kvwh, kvwl, kv_b, tab, Ksum, Mm);
    // Q GEMM (+elu/den/rope + fused Y = Qrot·Mt^T/den) -> Yh/Yl
    gemm_q<<<dim3(8, 32), 256, 0, stream>>>(xh, xl, qwh, qwl, q_b, tab, Ksum, Mm, Yh, Yl);
    // out = Y @ proj_w + proj_b
    gemm_out<<<dim3(8, 32), 256, 0, stream>>>(Yh, Yl, pwh, pwl, proj_b, (float*)d_out);
}

// Round 5
// 264.916 us; speedup vs baseline: 2.3786x; 1.0232x over previous
//
#include <hip/hip_runtime.h>
#include <cstddef>
#include <cstdint>

// Problem constants
#define B_SZ  2
#define T_SEQ 2048
#define S_SEQ 2048
#define C_EMB 1024
#define NH    16
#define HD    64
#define KDIM  1024   // inner dim of the three big GEMMs

typedef __attribute__((ext_vector_type(8))) short bf16x8;
typedef __attribute__((ext_vector_type(4))) float f32x4;

// ---------------------------------------------------------------------------
// Workspace layout (float units).
// ---------------------------------------------------------------------------
#define OFF_XH    ((size_t)0)           // [4096,1024] ushort
#define OFF_XL    ((size_t)2097152)
#define OFF_MEMH  ((size_t)4194304)     // [4096,1024] ushort
#define OFF_MEML  ((size_t)6291456)
#define OFF_QWH   ((size_t)8388608)     // [1024,1024] ushort (transposed [N,K])
#define OFF_QWL   ((size_t)8912896)
#define OFF_KVWH  ((size_t)9437184)     // [2048,1024] ushort
#define OFF_KVWL  ((size_t)10485760)
#define OFF_PWH   ((size_t)11534336)    // [1024,1024] ushort
#define OFF_PWL   ((size_t)12058624)
#define OFF_KSUM  ((size_t)12582912)    // [2,1024]      (zeroed by prep)
#define OFF_MT    ((size_t)12584960)    // [32,64,64]    (zeroed by prep)
#define OFF_TAB   ((size_t)12716032)    // [2048,32] float2
#define OFF_YH    ((size_t)12847104)    // [4096,1024] ushort
#define OFF_YL    ((size_t)14944256)
#define WS_FLOATS ((size_t)17041408)    // ~68.2 MB

__device__ __forceinline__ float elu1(float v) {
    return v > 0.0f ? v + 1.0f : __expf(v);
}
__device__ __forceinline__ unsigned short bf16_rne(float x) {
    union { float f; unsigned int u; } v; v.f = x;
    unsigned int u = v.u;
    return (unsigned short)((u + 0x7FFFu + ((u >> 16) & 1u)) >> 16);
}
__device__ __forceinline__ float bf16_to_f(unsigned short h) {
    union { unsigned int u; float f; } v; v.u = ((unsigned int)h) << 16;
    return v.f;
}

// ---------------------------------------------------------------------------
// Unified prep kernel: block-range dispatch over
//   [0,4096)      x split            (fp32 -> bf16 hi/lo)
//   [4096,8192)   memory split
//   [8192,9216)   q_w  split+transpose (32x32 tiles)
//   [9216,11264)  kv_w split+transpose
//   [11264,12288) proj_w split+transpose
//   [12288,12544) rope cos/sin table
//   [12544,13064) zero Ksum+Mt (133120 floats)
// ---------------------------------------------------------------------------
#define PREP_BLOCKS 13064

__device__ __forceinline__ void split4_body(
    const float4* __restrict__ in, ushort4* __restrict__ hi,
    ushort4* __restrict__ lo, int i)
{
    float4 v = in[i];
    ushort4 h, l;
    h.x = bf16_rne(v.x); l.x = bf16_rne(v.x - bf16_to_f(h.x));
    h.y = bf16_rne(v.y); l.y = bf16_rne(v.y - bf16_to_f(h.y));
    h.z = bf16_rne(v.z); l.z = bf16_rne(v.z - bf16_to_f(h.z));
    h.w = bf16_rne(v.w); l.w = bf16_rne(v.w - bf16_to_f(h.w));
    hi[i] = h; lo[i] = l;
}

__device__ __forceinline__ void transpose_body(
    const float* __restrict__ W, unsigned short* __restrict__ Wth,
    unsigned short* __restrict__ Wtl, int K, int N, int bx, int by,
    float (*tile)[33])
{
    const int k0 = by * 32, n0 = bx * 32;
    const int tx = threadIdx.x & 31, ty = threadIdx.x >> 5;
    #pragma unroll
    for (int j = 0; j < 4; ++j)
        tile[ty + j * 8][tx] = W[(size_t)(k0 + ty + j * 8) * N + n0 + tx];
    __syncthreads();
    #pragma unroll
    for (int j = 0; j < 4; ++j) {
        float x = tile[tx][ty + j * 8];
        unsigned short h = bf16_rne(x);
        unsigned short l = bf16_rne(x - bf16_to_f(h));
        size_t o = (size_t)(n0 + ty + j * 8) * K + k0 + tx;
        Wth[o] = h; Wtl[o] = l;
    }
}

__global__ __launch_bounds__(256) void prep_kernel(
    const float* __restrict__ x, const float* __restrict__ memory,
    const float* __restrict__ q_w, const float* __restrict__ kv_w,
    const float* __restrict__ proj_w,
    unsigned short* __restrict__ xh, unsigned short* __restrict__ xl,
    unsigned short* __restrict__ mh, unsigned short* __restrict__ ml,
    unsigned short* __restrict__ qwh, unsigned short* __restrict__ qwl,
    unsigned short* __restrict__ kvwh, unsigned short* __restrict__ kvwl,
    unsigned short* __restrict__ pwh, unsigned short* __restrict__ pwl,
    float2* __restrict__ tab, float* __restrict__ zero_base)
{
    __shared__ float tile[32][33];
    const int bid = blockIdx.x;
    const int tid = threadIdx.x;
    if (bid < 4096) {
        split4_body((const float4*)x, (ushort4*)xh, (ushort4*)xl, bid * 256 + tid);
    } else if (bid < 8192) {
        split4_body((const float4*)memory, (ushort4*)mh, (ushort4*)ml, (bid - 4096) * 256 + tid);
    } else if (bid < 9216) {
        int i = bid - 8192;
        transpose_body(q_w, qwh, qwl, 1024, 1024, i & 31, i >> 5, tile);
    } else if (bid < 11264) {
        int i = bid - 9216;
        transpose_body(kv_w, kvwh, kvwl, 1024, 2048, i & 63, i >> 6, tile);
    } else if (bid < 12288) {
        int i = bid - 11264;
        transpose_body(proj_w, pwh, pwl, 1024, 1024, i & 31, i >> 5, tile);
    } else if (bid < 12544) {
        int idx = (bid - 12288) * 256 + tid;    // pos*32 + i
        int pos = idx >> 5, i = idx & 31;
        double invf = exp(-(double)i * (9.210340371976184 / 32.0));  // 10000^(-i/32)
        float arg = (float)((double)pos * invf);
        float sn, cs;
        sincosf(arg, &sn, &cs);
        tab[idx] = make_float2(cs, sn);
    } else {
        int idx = (bid - 12544) * 256 + tid;
        if (idx < 2048 + 131072) zero_base[idx] = 0.0f;   // Ksum + Mt
    }
}

// ---------------------------------------------------------------------------
// Generic bf16x3 MFMA main loop (A rows m0.., B^T rows n0..). Fills acc[4][4].
// ---------------------------------------------------------------------------
__device__ __forceinline__ void gemm_main_loop(
    const unsigned short* __restrict__ Ah, const unsigned short* __restrict__ Al,
    const unsigned short* __restrict__ Bth, const unsigned short* __restrict__ Btl,
    unsigned short* lds, int m0, int n0, f32x4 acc[4][4])
{
    const int tid = threadIdx.x;
    const int w = tid >> 6, lane = tid & 63;
    const int wr = w >> 1, wc = w & 1;
    const int quad = lane >> 4, lrow = lane & 15;

    const unsigned short* src = (w == 0) ? Ah : (w == 1) ? Al : (w == 2) ? Bth : Btl;
    const int rbase = (w < 2) ? m0 : n0;
    const int srow = lane >> 2;
    const int scol = (lane & 3) * 8;
    const unsigned short* gsrc = src + (size_t)(rbase + srow) * KDIM + scol;
    unsigned short* lbase = &lds[w * 4096];

    const unsigned short* As_h = lds;
    const unsigned short* As_l = lds + 4096;
    const unsigned short* Bs_h = lds + 8192;
    const unsigned short* Bs_l = lds + 12288;

    for (int k0 = 0; k0 < KDIM; k0 += 32) {
        #pragma unroll
        for (int i = 0; i < 8; ++i) {
            __builtin_amdgcn_global_load_lds(
                (const __attribute__((address_space(1))) unsigned int*)(gsrc + (size_t)i * 16 * KDIM + k0),
                (__attribute__((address_space(3))) unsigned int*)(lbase + i * 512),
                16, 0, 0);
        }
        __syncthreads();

        bf16x8 bh[4], bl[4];
        #pragma unroll
        for (int jt = 0; jt < 4; ++jt) {
            int nl = wc * 64 + jt * 16 + lrow;
            bh[jt] = *(const bf16x8*)&Bs_h[nl * 32 + quad * 8];
            bl[jt] = *(const bf16x8*)&Bs_l[nl * 32 + quad * 8];
        }
        #pragma unroll
        for (int it = 0; it < 4; ++it) {
            int ml = wr * 64 + it * 16 + lrow;
            bf16x8 ah = *(const bf16x8*)&As_h[ml * 32 + quad * 8];
            bf16x8 al = *(const bf16x8*)&As_l[ml * 32 + quad * 8];
            #pragma unroll
            for (int jt = 0; jt < 4; ++jt) {
                acc[it][jt] = __builtin_amdgcn_mfma_f32_16x16x32_bf16(ah, bh[jt], acc[it][jt], 0, 0, 0);
                acc[it][jt] = __builtin_amdgcn_mfma_f32_16x16x32_bf16(ah, bl[jt], acc[it][jt], 0, 0, 0);
                acc[it][jt] = __builtin_amdgcn_mfma_f32_16x16x32_bf16(al, bh[jt], acc[it][jt], 0, 0, 0);
            }
        }
        __syncthreads();
    }
}

// ---------------------------------------------------------------------------
// KV GEMM, head-paired columns: block (h, mtile) computes K-slice (cols
// h*64..) and V-slice (cols 1024+h*64..) for 128 memory rows. Epilogue:
// bias, elu+1(K), Ksum atomics, RoPE in registers, LDS transpose ->
// Mt[d2][d1] += V^T Krot via MFMA + atomicAdd. No K/V global output.
// grid (16 heads, 32 mtiles).
// ---------------------------------------------------------------------------
__global__ __launch_bounds__(256) void gemm_kv(
    const unsigned short* __restrict__ Ah, const unsigned short* __restrict__ Al,
    const unsigned short* __restrict__ Bth, const unsigned short* __restrict__ Btl,
    const float* __restrict__ bias, const float2* __restrict__ tab,
    float* __restrict__ Ksum, float* __restrict__ Mt)
{
    // main loop uses [0,16384); epilogue reuses all 34816 (KH/KL/VH/VL, 64x136)
    __shared__ unsigned short smem[34816];
    const int tid = threadIdx.x;
    const int w = tid >> 6, lane = tid & 63;
    const int wr = w >> 1, wc = w & 1;
    const int quad = lane >> 4, lrow = lane & 15;
    const int h  = blockIdx.x;
    const int m0 = blockIdx.y * 128;
    const int b  = m0 >> 11;
    const int tbase = (m0 & 2047) + wr * 64;

    // ---- main loop (B rows remapped: local col>=64 -> +960) ----
    {
        const unsigned short* src = (w == 0) ? Ah : (w == 1) ? Al : (w == 2) ? Bth : Btl;
        const int srow = lane >> 2, scol = (lane & 3) * 8;
        const size_t rowbase = (w < 2) ? (size_t)(m0 + srow) : (size_t)(h * 64 + srow);
        const unsigned short* gsrc = src + rowbase * KDIM + scol;
        const size_t vskip = (w >= 2) ? (size_t)960 * KDIM : 0;
        unsigned short* lbase = &smem[w * 4096];
        const unsigned short* As_h = smem;
        const unsigned short* As_l = smem + 4096;
        const unsigned short* Bs_h = smem + 8192;
        const unsigned short* Bs_l = smem + 12288;

        f32x4 acc[4][4] = {};
        for (int k0 = 0; k0 < KDIM; k0 += 32) {
            #pragma unroll
            for (int i = 0; i < 8; ++i) {
                size_t goff = (size_t)i * 16 * KDIM + k0 + ((i >= 4) ? vskip : 0);
                __builtin_amdgcn_global_load_lds(
                    (const __attribute__((address_space(1))) unsigned int*)(gsrc + goff),
                    (__attribute__((address_space(3))) unsigned int*)(lbase + i * 512),
                    16, 0, 0);
            }
            __syncthreads();
            bf16x8 bh[4], bl[4];
            #pragma unroll
            for (int jt = 0; jt < 4; ++jt) {
                int nl = wc * 64 + jt * 16 + lrow;
                bh[jt] = *(const bf16x8*)&Bs_h[nl * 32 + quad * 8];
                bl[jt] = *(const bf16x8*)&Bs_l[nl * 32 + quad * 8];
            }
            #pragma unroll
            for (int it = 0; it < 4; ++it) {
                int ml = wr * 64 + it * 16 + lrow;
                bf16x8 ah = *(const bf16x8*)&As_h[ml * 32 + quad * 8];
                bf16x8 al = *(const bf16x8*)&As_l[ml * 32 + quad * 8];
                #pragma unroll
                for (int jt = 0; jt < 4; ++jt) {
                    acc[it][jt] = __builtin_amdgcn_mfma_f32_16x16x32_bf16(ah, bh[jt], acc[it][jt], 0, 0, 0);
                    acc[it][jt] = __builtin_amdgcn_mfma_f32_16x16x32_bf16(ah, bl[jt], acc[it][jt], 0, 0, 0);
                    acc[it][jt] = __builtin_amdgcn_mfma_f32_16x16x32_bf16(al, bh[jt], acc[it][jt], 0, 0, 0);
                }
            }
            __syncthreads();
        }

        // ---- epilogue part 1: bias / elu / Ksum / rope, then LDS transpose ----
        const bool isK = (wc == 0);
        const int colg = (isK ? 0 : C_EMB) + h * 64;
        float bb[4];
        #pragma unroll
        for (int jt = 0; jt < 4; ++jt) bb[jt] = bias[colg + jt * 16 + lrow];
        #pragma unroll
        for (int it = 0; it < 4; ++it)
            #pragma unroll
            for (int jt = 0; jt < 4; ++jt)
                #pragma unroll
                for (int r = 0; r < 4; ++r) {
                    float v = acc[it][jt][r] + bb[jt];
                    acc[it][jt][r] = isK ? elu1(v) : v;
                }

        if (isK) {
            #pragma unroll
            for (int jt = 0; jt < 4; ++jt) {
                float p = 0.0f;
                #pragma unroll
                for (int it = 0; it < 4; ++it)
                    #pragma unroll
                    for (int r = 0; r < 4; ++r) p += acc[it][jt][r];
                p += __shfl_xor(p, 16);
                p += __shfl_xor(p, 32);
                if (quad == 0)
                    atomicAdd(&Ksum[b * C_EMB + h * 64 + jt * 16 + lrow], p);
            }
            #pragma unroll
            for (int it = 0; it < 4; ++it)
                #pragma unroll
                for (int r = 0; r < 4; ++r) {
                    int s = tbase + it * 16 + quad * 4 + r;
                    float2 c0 = tab[s * 32 + lrow];
                    float2 c1 = tab[s * 32 + 16 + lrow];
                    float a0 = acc[it][0][r], a1 = acc[it][1][r];
                    float a2 = acc[it][2][r], a3 = acc[it][3][r];
                    acc[it][0][r] = a0 * c0.x - a2 * c0.y;
                    acc[it][2][r] = a2 * c0.x + a0 * c0.y;
                    acc[it][1][r] = a1 * c1.x - a3 * c1.y;
                    acc[it][3][r] = a3 * c1.x + a1 * c1.y;
                }
        }

        // transposed LDS: K_hi[64][136] @0, K_lo @8704, V_hi @17408, V_lo @26112
        unsigned short* Hd = smem + (isK ? 0 : 17408);
        unsigned short* Ld = Hd + 8704;
        #pragma unroll
        for (int jt = 0; jt < 4; ++jt) {
            int d = jt * 16 + lrow;
            #pragma unroll
            for (int it = 0; it < 4; ++it) {
                int t0loc = wr * 64 + it * 16 + quad * 4;
                ushort4 h4, l4;
                float v0 = acc[it][jt][0], v1 = acc[it][jt][1];
                float v2 = acc[it][jt][2], v3 = acc[it][jt][3];
                h4.x = bf16_rne(v0); l4.x = bf16_rne(v0 - bf16_to_f(h4.x));
                h4.y = bf16_rne(v1); l4.y = bf16_rne(v1 - bf16_to_f(h4.y));
                h4.z = bf16_rne(v2); l4.z = bf16_rne(v2 - bf16_to_f(h4.z));
                h4.w = bf16_rne(v3); l4.w = bf16_rne(v3 - bf16_to_f(h4.w));
                *(ushort4*)&Hd[d * 136 + t0loc] = h4;
                *(ushort4*)&Ld[d * 136 + t0loc] = l4;
            }
        }
    }
    __syncthreads();

    // ---- epilogue part 2: Mt[d2][d1] += sum_t V[t][d2]*Krot[t][d1] ----
    {
        const unsigned short* KH = smem;
        const unsigned short* KL = smem + 8704;
        const unsigned short* VH = smem + 17408;
        const unsigned short* VL = smem + 26112;
        const int mrow = w * 16 + lrow;          // d2 strip per wave
        f32x4 macc[4] = {};
        #pragma unroll
        for (int ks = 0; ks < 4; ++ks) {
            int kof = ks * 32 + quad * 8;
            bf16x8 vah = *(const bf16x8*)&VH[mrow * 136 + kof];
            bf16x8 val = *(const bf16x8*)&VL[mrow * 136 + kof];
            #pragma unroll
            for (int jt = 0; jt < 4; ++jt) {
                int nrow = jt * 16 + lrow;       // d1
                bf16x8 kbh = *(const bf16x8*)&KH[nrow * 136 + kof];
                bf16x8 kbl = *(const bf16x8*)&KL[nrow * 136 + kof];
                macc[jt] = __builtin_amdgcn_mfma_f32_16x16x32_bf16(vah, kbh, macc[jt], 0, 0, 0);
                macc[jt] = __builtin_amdgcn_mfma_f32_16x16x32_bf16(vah, kbl, macc[jt], 0, 0, 0);
                macc[jt] = __builtin_amdgcn_mfma_f32_16x16x32_bf16(val, kbh, macc[jt], 0, 0, 0);
            }
        }
        const int bh = b * NH + h;
        #pragma unroll
        for (int jt = 0; jt < 4; ++jt)
            #pragma unroll
            for (int r = 0; r < 4; ++r)
                atomicAdd(&Mt[((size_t)bh * 64 + w * 16 + quad * 4 + r) * 64 + jt * 16 + lrow],
                          macc[jt][r]);
    }
}

// ---------------------------------------------------------------------------
// Q GEMM + full attention epilogue: bias, elu+1, den in registers, RoPE,
// Qrot -> per-wave LDS, Y = (Qrot @ Mt^T)/den via MFMA, bf16 hi/lo stores.
// Each wave's 64 cols = one complete head. grid (8, 32).
// ---------------------------------------------------------------------------
__global__ __launch_bounds__(256) void gemm_q(
    const unsigned short* __restrict__ Ah, const unsigned short* __restrict__ Al,
    const unsigned short* __restrict__ Bth, const unsigned short* __restrict__ Btl,
    const float* __restrict__ bias, const float2* __restrict__ tab,
    const float* __restrict__ Ksum, const float* __restrict__ Mt,
    unsigned short* __restrict__ Yh, unsigned short* __restrict__ Yl)
{
    // main loop uses [0,16384); epilogue per-wave Qrot hi/lo [64][72] @ w*9216
    __shared__ unsigned short smem[36864];
    const int m0 = blockIdx.y * 128, n0 = blockIdx.x * 128;
    f32x4 acc[4][4] = {};
    gemm_main_loop(Ah, Al, Bth, Btl, smem, m0, n0, acc);

    const int tid = threadIdx.x;
    const int w = tid >> 6, lane = tid & 63;
    const int wr = w >> 1, wc = w & 1;
    const int quad = lane >> 4, lrow = lane & 15;
    const int h = blockIdx.x * 2 + wc;
    const int b = m0 >> 11;
    const int tbase = (m0 & 2047) + wr * 64;
    const int bh = b * NH + h;

    float bb[4];
    #pragma unroll
    for (int jt = 0; jt < 4; ++jt) bb[jt] = bias[h * 64 + jt * 16 + lrow];
    #pragma unroll
    for (int it = 0; it < 4; ++it)
        #pragma unroll
        for (int jt = 0; jt < 4; ++jt)
            #pragma unroll
            for (int r = 0; r < 4; ++r)
                acc[it][jt][r] = elu1(acc[it][jt][r] + bb[jt]);

    // den (pre-rope), kept in registers (uniform over lrow after reduction)
    float ks[4], den_reg[4][4];
    #pragma unroll
    for (int jt = 0; jt < 4; ++jt) ks[jt] = Ksum[b * C_EMB + h * 64 + jt * 16 + lrow];
    #pragma unroll
    for (int it = 0; it < 4; ++it)
        #pragma unroll
        for (int r = 0; r < 4; ++r) {
            float p = acc[it][0][r] * ks[0] + acc[it][1][r] * ks[1]
                    + acc[it][2][r] * ks[2] + acc[it][3][r] * ks[3];
            p += __shfl_xor(p, 1);
            p += __shfl_xor(p, 2);
            p += __shfl_xor(p, 4);
            p += __shfl_xor(p, 8);
            den_reg[it][r] = p;
        }

    // RoPE in registers
    #pragma unroll
    for (int it = 0; it < 4; ++it)
        #pragma unroll
        for (int r = 0; r < 4; ++r) {
            int s = tbase + it * 16 + quad * 4 + r;
            float2 c0 = tab[s * 32 + lrow];
            float2 c1 = tab[s * 32 + 16 + lrow];
            float a0 = acc[it][0][r], a1 = acc[it][1][r];
            float a2 = acc[it][2][r], a3 = acc[it][3][r];
            acc[it][0][r] = a0 * c0.x - a2 * c0.y;
            acc[it][2][r] = a2 * c0.x + a0 * c0.y;
            acc[it][1][r] = a1 * c1.x - a3 * c1.y;
            acc[it][3][r] = a3 * c1.x + a1 * c1.y;
        }

    // Qrot -> per-wave LDS (row-major [t][d], stride 72)
    unsigned short* QH = smem + w * 9216;
    unsigned short* QL = QH + 4608;
    #pragma unroll
    for (int it = 0; it < 4; ++it)
        #pragma unroll
        for (int jt = 0; jt < 4; ++jt)
            #pragma unroll
            for (int r = 0; r < 4; ++r) {
                int tloc = it * 16 + quad * 4 + r;
                int d = jt * 16 + lrow;
                float v = acc[it][jt][r];
                unsigned short hh = bf16_rne(v);
                QH[tloc * 72 + d] = hh;
                QL[tloc * 72 + d] = bf16_rne(v - bf16_to_f(hh));
            }
    __syncthreads();

    // Y = (Qrot @ Mt^T) / den
    f32x4 acc2[4][4] = {};
    #pragma unroll
    for (int kc = 0; kc < 2; ++kc) {
        bf16x8 mbh[4], mbl[4];
        #pragma unroll
        for (int jt2 = 0; jt2 < 4; ++jt2) {
            const float* mp = &Mt[((size_t)bh * 64 + jt2 * 16 + lrow) * 64 + kc * 32 + quad * 8];
            #pragma unroll
            for (int e = 0; e < 8; ++e) {
                float x = mp[e];
                unsigned short hh = bf16_rne(x);
                mbh[jt2][e] = (short)hh;
                mbl[jt2][e] = (short)bf16_rne(x - bf16_to_f(hh));
            }
        }
        #pragma unroll
        for (int it2 = 0; it2 < 4; ++it2) {
            int ro = (it2 * 16 + lrow) * 72 + kc * 32 + quad * 8;
            bf16x8 qh = *(const bf16x8*)&QH[ro];
            bf16x8 ql = *(const bf16x8*)&QL[ro];
            #pragma unroll
            for (int jt2 = 0; jt2 < 4; ++jt2) {
                acc2[it2][jt2] = __builtin_amdgcn_mfma_f32_16x16x32_bf16(qh, mbh[jt2], acc2[it2][jt2], 0, 0, 0);
                acc2[it2][jt2] = __builtin_amdgcn_mfma_f32_16x16x32_bf16(qh, mbl[jt2], acc2[it2][jt2], 0, 0, 0);
                acc2[it2][jt2] = __builtin_amdgcn_mfma_f32_16x16x32_bf16(ql, mbh[jt2], acc2[it2][jt2], 0, 0, 0);
            }
        }
    }

    // divide + bf16 hi/lo store
    #pragma unroll
    for (int it2 = 0; it2 < 4; ++it2)
        #pragma unroll
        for (int jt2 = 0; jt2 < 4; ++jt2)
            #pragma unroll
            for (int r = 0; r < 4; ++r) {
                float v = acc2[it2][jt2][r] / den_reg[it2][r];
                size_t o = ((size_t)(m0 + wr * 64 + it2 * 16 + quad * 4 + r)) * C_EMB
                         + h * 64 + jt2 * 16 + lrow;
                unsigned short hh = bf16_rne(v);
                Yh[o] = hh;
                Yl[o] = bf16_rne(v - bf16_to_f(hh));
            }
}

// ---------------------------------------------------------------------------
// Output projection GEMM: out = Y @ proj_w + proj_b (fp32 out). N = 1024.
// ---------------------------------------------------------------------------
__global__ __launch_bounds__(256) void gemm_out(
    const unsigned short* __restrict__ Ah, const unsigned short* __restrict__ Al,
    const unsigned short* __restrict__ Bth, const unsigned short* __restrict__ Btl,
    const float* __restrict__ bias, float* __restrict__ out)
{
    __shared__ unsigned short lds[16384];
    const int m0 = blockIdx.y * 128, n0 = blockIdx.x * 128;
    f32x4 acc[4][4] = {};
    gemm_main_loop(Ah, Al, Bth, Btl, lds, m0, n0, acc);

    const int tid = threadIdx.x;
    const int w = tid >> 6, lane = tid & 63;
    const int wr = w >> 1, wc = w & 1;
    const int quad = lane >> 4, lrow = lane & 15;

    #pragma unroll
    for (int jt = 0; jt < 4; ++jt) {
        int gc = n0 + wc * 64 + jt * 16 + lrow;
        float bb = bias[gc];
        #pragma unroll
        for (int it = 0; it < 4; ++it) {
            int grb = m0 + wr * 64 + it * 16 + quad * 4;
            #pragma unroll
            for (int r = 0; r < 4; ++r)
                out[(size_t)(grb + r) * C_EMB + gc] = acc[it][jt][r] + bb;
        }
    }
}

// ---------------------------------------------------------------------------
extern "C" void kernel_launch(void* const* d_in, const int* in_sizes, int n_in,
                              void* d_out, int out_size, void* d_ws, size_t ws_size,
                              hipStream_t stream)
{
    const float* x      = (const float*)d_in[0];
    const float* memory = (const float*)d_in[1];
    const float* q_w    = (const float*)d_in[2];
    const float* q_b    = (const float*)d_in[3];
    const float* kv_w   = (const float*)d_in[4];
    const float* kv_b   = (const float*)d_in[5];
    const float* proj_w = (const float*)d_in[6];
    const float* proj_b = (const float*)d_in[7];

    if (ws_size < WS_FLOATS * sizeof(float)) return;

    float* ws = (float*)d_ws;
    unsigned short* xh   = (unsigned short*)(ws + OFF_XH);
    unsigned short* xl   = (unsigned short*)(ws + OFF_XL);
    unsigned short* mh   = (unsigned short*)(ws + OFF_MEMH);
    unsigned short* ml   = (unsigned short*)(ws + OFF_MEML);
    unsigned short* qwh  = (unsigned short*)(ws + OFF_QWH);
    unsigned short* qwl  = (unsigned short*)(ws + OFF_QWL);
    unsigned short* kvwh = (unsigned short*)(ws + OFF_KVWH);
    unsigned short* kvwl = (unsigned short*)(ws + OFF_KVWL);
    unsigned short* pwh  = (unsigned short*)(ws + OFF_PWH);
    unsigned short* pwl  = (unsigned short*)(ws + OFF_PWL);
    unsigned short* Yh   = (unsigned short*)(ws + OFF_YH);
    unsigned short* Yl   = (unsigned short*)(ws + OFF_YL);
    float*  Ksum = ws + OFF_KSUM;
    float*  Mm   = ws + OFF_MT;
    float2* tab  = (float2*)(ws + OFF_TAB);

    // One prep dispatch: splits + weight transposes + rope table + zero Ksum/Mt
    prep_kernel<<<PREP_BLOCKS, 256, 0, stream>>>(
        x, memory, q_w, kv_w, proj_w,
        xh, xl, mh, ml, qwh, qwl, kvwh, kvwl, pwh, pwl,
        tab, Ksum /* zero_base: Ksum+Mt contiguous */);

    // KV GEMM (+elu/Ksum/rope + fused Mt accumulate). No K/V global output.
    gemm_kv<<<dim3(16, 32), 256, 0, stream>>>(mh, ml, kvwh, kvwl, kv_b, tab, Ksum, Mm);
    // Q GEMM (+elu/den/rope + fused Y = Qrot·Mt^T/den) -> Yh/Yl
    gemm_q<<<dim3(8, 32), 256, 0, stream>>>(xh, xl, qwh, qwl, q_b, tab, Ksum, Mm, Yh, Yl);
    // out = Y @ proj_w + proj_b
    gemm_out<<<dim3(8, 32), 256, 0, stream>>>(Yh, Yl, pwh, pwl, proj_b, (float*)d_out);
}

// Round 6
// 248.396 us; speedup vs baseline: 2.5368x; 1.0665x over previous
//
#include <hip/hip_runtime.h>
#include <cstddef>
#include <cstdint>

// Problem constants
#define B_SZ  2
#define T_SEQ 2048
#define S_SEQ 2048
#define C_EMB 1024
#define NH    16
#define HD    64
#define KDIM  1024   // inner dim of the three big GEMMs

typedef __attribute__((ext_vector_type(8))) short bf16x8;
typedef __attribute__((ext_vector_type(4))) float f32x4;

// ---------------------------------------------------------------------------
// Workspace layout (float units).
// ---------------------------------------------------------------------------
#define OFF_XH    ((size_t)0)           // [4096,1024] ushort
#define OFF_XL    ((size_t)2097152)
#define OFF_MEMH  ((size_t)4194304)     // [4096,1024] ushort
#define OFF_MEML  ((size_t)6291456)
#define OFF_QWH   ((size_t)8388608)     // [1024,1024] ushort (transposed [N,K])
#define OFF_QWL   ((size_t)8912896)
#define OFF_KVWH  ((size_t)9437184)     // [2048,1024] ushort
#define OFF_KVWL  ((size_t)10485760)
#define OFF_PWH   ((size_t)11534336)    // [1024,1024] ushort
#define OFF_PWL   ((size_t)12058624)
#define OFF_KSUM  ((size_t)12582912)    // [2,1024]      (zeroed by prep)
#define OFF_MT    ((size_t)12584960)    // [32,64,64]    (zeroed by prep)
#define OFF_TAB   ((size_t)12716032)    // [2048,32] float2
#define OFF_YH    ((size_t)12847104)    // [4096,1024] ushort
#define OFF_YL    ((size_t)14944256)
#define WS_FLOATS ((size_t)17041408)    // ~68.2 MB

__device__ __forceinline__ float elu1(float v) {
    return v > 0.0f ? v + 1.0f : __expf(v);
}
__device__ __forceinline__ unsigned short bf16_rne(float x) {
    union { float f; unsigned int u; } v; v.f = x;
    unsigned int u = v.u;
    return (unsigned short)((u + 0x7FFFu + ((u >> 16) & 1u)) >> 16);
}
__device__ __forceinline__ float bf16_to_f(unsigned short h) {
    union { unsigned int u; float f; } v; v.u = ((unsigned int)h) << 16;
    return v.f;
}

// ---------------------------------------------------------------------------
// Unified prep kernel (block-range dispatch), unchanged from R5.
// ---------------------------------------------------------------------------
#define PREP_BLOCKS 13064

__device__ __forceinline__ void split4_body(
    const float4* __restrict__ in, ushort4* __restrict__ hi,
    ushort4* __restrict__ lo, int i)
{
    float4 v = in[i];
    ushort4 h, l;
    h.x = bf16_rne(v.x); l.x = bf16_rne(v.x - bf16_to_f(h.x));
    h.y = bf16_rne(v.y); l.y = bf16_rne(v.y - bf16_to_f(h.y));
    h.z = bf16_rne(v.z); l.z = bf16_rne(v.z - bf16_to_f(h.z));
    h.w = bf16_rne(v.w); l.w = bf16_rne(v.w - bf16_to_f(h.w));
    hi[i] = h; lo[i] = l;
}

__device__ __forceinline__ void transpose_body(
    const float* __restrict__ W, unsigned short* __restrict__ Wth,
    unsigned short* __restrict__ Wtl, int K, int N, int bx, int by,
    float (*tile)[33])
{
    const int k0 = by * 32, n0 = bx * 32;
    const int tx = threadIdx.x & 31, ty = threadIdx.x >> 5;
    #pragma unroll
    for (int j = 0; j < 4; ++j)
        tile[ty + j * 8][tx] = W[(size_t)(k0 + ty + j * 8) * N + n0 + tx];
    __syncthreads();
    #pragma unroll
    for (int j = 0; j < 4; ++j) {
        float x = tile[tx][ty + j * 8];
        unsigned short h = bf16_rne(x);
        unsigned short l = bf16_rne(x - bf16_to_f(h));
        size_t o = (size_t)(n0 + ty + j * 8) * K + k0 + tx;
        Wth[o] = h; Wtl[o] = l;
    }
}

__global__ __launch_bounds__(256) void prep_kernel(
    const float* __restrict__ x, const float* __restrict__ memory,
    const float* __restrict__ q_w, const float* __restrict__ kv_w,
    const float* __restrict__ proj_w,
    unsigned short* __restrict__ xh, unsigned short* __restrict__ xl,
    unsigned short* __restrict__ mh, unsigned short* __restrict__ ml,
    unsigned short* __restrict__ qwh, unsigned short* __restrict__ qwl,
    unsigned short* __restrict__ kvwh, unsigned short* __restrict__ kvwl,
    unsigned short* __restrict__ pwh, unsigned short* __restrict__ pwl,
    float2* __restrict__ tab, float* __restrict__ zero_base)
{
    __shared__ float tile[32][33];
    const int bid = blockIdx.x;
    const int tid = threadIdx.x;
    if (bid < 4096) {
        split4_body((const float4*)x, (ushort4*)xh, (ushort4*)xl, bid * 256 + tid);
    } else if (bid < 8192) {
        split4_body((const float4*)memory, (ushort4*)mh, (ushort4*)ml, (bid - 4096) * 256 + tid);
    } else if (bid < 9216) {
        int i = bid - 8192;
        transpose_body(q_w, qwh, qwl, 1024, 1024, i & 31, i >> 5, tile);
    } else if (bid < 11264) {
        int i = bid - 9216;
        transpose_body(kv_w, kvwh, kvwl, 1024, 2048, i & 63, i >> 6, tile);
    } else if (bid < 12288) {
        int i = bid - 11264;
        transpose_body(proj_w, pwh, pwl, 1024, 1024, i & 31, i >> 5, tile);
    } else if (bid < 12544) {
        int idx = (bid - 12288) * 256 + tid;    // pos*32 + i
        int pos = idx >> 5, i = idx & 31;
        double invf = exp(-(double)i * (9.210340371976184 / 32.0));  // 10000^(-i/32)
        float arg = (float)((double)pos * invf);
        float sn, cs;
        sincosf(arg, &sn, &cs);
        tab[idx] = make_float2(cs, sn);
    } else {
        int idx = (bid - 12544) * 256 + tid;
        if (idx < 2048 + 131072) zero_base[idx] = 0.0f;   // Ksum + Mt
    }
}

// ---------------------------------------------------------------------------
// 128(M)x64(N) bf16x3 MFMA main loop. 4 waves stacked along M (wave w: rows
// w*32..w*32+31, all 64 cols). BK=32. LDS: Ah[0,4096) Al[4096,8192)
// Bh[8192,10240) Bl[10240,12288). Fills acc[2][4].
// ---------------------------------------------------------------------------
__device__ __forceinline__ void gemm_main_loop_64(
    const unsigned short* __restrict__ Ah, const unsigned short* __restrict__ Al,
    const unsigned short* __restrict__ Bth, const unsigned short* __restrict__ Btl,
    unsigned short* lds, int m0, int n0, f32x4 acc[2][4])
{
    const int tid = threadIdx.x;
    const int w = tid >> 6, lane = tid & 63;
    const int quad = lane >> 4, lrow = lane & 15;
    const int srow = lane >> 2;
    const int scol = (lane & 3) * 8;

    const unsigned short* src = (w == 0) ? Ah : (w == 1) ? Al : (w == 2) ? Bth : Btl;
    const int rbase = (w < 2) ? m0 : n0;
    const unsigned short* gsrc = src + (size_t)(rbase + srow) * KDIM + scol;
    unsigned short* lbase = (w < 2) ? &lds[w * 4096] : &lds[8192 + (w - 2) * 2048];

    const unsigned short* As_h = lds;
    const unsigned short* As_l = lds + 4096;
    const unsigned short* Bs_h = lds + 8192;
    const unsigned short* Bs_l = lds + 10240;

    for (int k0 = 0; k0 < KDIM; k0 += 32) {
        if (w < 2) {
            #pragma unroll
            for (int i = 0; i < 8; ++i)
                __builtin_amdgcn_global_load_lds(
                    (const __attribute__((address_space(1))) unsigned int*)(gsrc + (size_t)i * 16 * KDIM + k0),
                    (__attribute__((address_space(3))) unsigned int*)(lbase + i * 512),
                    16, 0, 0);
        } else {
            #pragma unroll
            for (int i = 0; i < 4; ++i)
                __builtin_amdgcn_global_load_lds(
                    (const __attribute__((address_space(1))) unsigned int*)(gsrc + (size_t)i * 16 * KDIM + k0),
                    (__attribute__((address_space(3))) unsigned int*)(lbase + i * 512),
                    16, 0, 0);
        }
        __syncthreads();

        bf16x8 bh[4], bl[4];
        #pragma unroll
        for (int jt = 0; jt < 4; ++jt) {
            int nl = jt * 16 + lrow;
            bh[jt] = *(const bf16x8*)&Bs_h[nl * 32 + quad * 8];
            bl[jt] = *(const bf16x8*)&Bs_l[nl * 32 + quad * 8];
        }
        #pragma unroll
        for (int it = 0; it < 2; ++it) {
            int ml = w * 32 + it * 16 + lrow;
            bf16x8 ah = *(const bf16x8*)&As_h[ml * 32 + quad * 8];
            bf16x8 al = *(const bf16x8*)&As_l[ml * 32 + quad * 8];
            #pragma unroll
            for (int jt = 0; jt < 4; ++jt) {
                acc[it][jt] = __builtin_amdgcn_mfma_f32_16x16x32_bf16(ah, bh[jt], acc[it][jt], 0, 0, 0);
                acc[it][jt] = __builtin_amdgcn_mfma_f32_16x16x32_bf16(ah, bl[jt], acc[it][jt], 0, 0, 0);
                acc[it][jt] = __builtin_amdgcn_mfma_f32_16x16x32_bf16(al, bh[jt], acc[it][jt], 0, 0, 0);
            }
        }
        __syncthreads();
    }
}

// ---------------------------------------------------------------------------
// KV GEMM (unchanged from R5): 128x128 head-paired tile, fused elu/Ksum/rope
// + Mt accumulate. grid (16 heads, 32 mtiles).
// ---------------------------------------------------------------------------
__global__ __launch_bounds__(256) void gemm_kv(
    const unsigned short* __restrict__ Ah, const unsigned short* __restrict__ Al,
    const unsigned short* __restrict__ Bth, const unsigned short* __restrict__ Btl,
    const float* __restrict__ bias, const float2* __restrict__ tab,
    float* __restrict__ Ksum, float* __restrict__ Mt)
{
    __shared__ unsigned short smem[34816];
    const int tid = threadIdx.x;
    const int w = tid >> 6, lane = tid & 63;
    const int wr = w >> 1, wc = w & 1;
    const int quad = lane >> 4, lrow = lane & 15;
    const int h  = blockIdx.x;
    const int m0 = blockIdx.y * 128;
    const int b  = m0 >> 11;
    const int tbase = (m0 & 2047) + wr * 64;

    {
        const unsigned short* src = (w == 0) ? Ah : (w == 1) ? Al : (w == 2) ? Bth : Btl;
        const int srow = lane >> 2, scol = (lane & 3) * 8;
        const size_t rowbase = (w < 2) ? (size_t)(m0 + srow) : (size_t)(h * 64 + srow);
        const unsigned short* gsrc = src + rowbase * KDIM + scol;
        const size_t vskip = (w >= 2) ? (size_t)960 * KDIM : 0;
        unsigned short* lbase = &smem[w * 4096];
        const unsigned short* As_h = smem;
        const unsigned short* As_l = smem + 4096;
        const unsigned short* Bs_h = smem + 8192;
        const unsigned short* Bs_l = smem + 12288;

        f32x4 acc[4][4] = {};
        for (int k0 = 0; k0 < KDIM; k0 += 32) {
            #pragma unroll
            for (int i = 0; i < 8; ++i) {
                size_t goff = (size_t)i * 16 * KDIM + k0 + ((i >= 4) ? vskip : 0);
                __builtin_amdgcn_global_load_lds(
                    (const __attribute__((address_space(1))) unsigned int*)(gsrc + goff),
                    (__attribute__((address_space(3))) unsigned int*)(lbase + i * 512),
                    16, 0, 0);
            }
            __syncthreads();
            bf16x8 bh[4], bl[4];
            #pragma unroll
            for (int jt = 0; jt < 4; ++jt) {
                int nl = wc * 64 + jt * 16 + lrow;
                bh[jt] = *(const bf16x8*)&Bs_h[nl * 32 + quad * 8];
                bl[jt] = *(const bf16x8*)&Bs_l[nl * 32 + quad * 8];
            }
            #pragma unroll
            for (int it = 0; it < 4; ++it) {
                int ml = wr * 64 + it * 16 + lrow;
                bf16x8 ah = *(const bf16x8*)&As_h[ml * 32 + quad * 8];
                bf16x8 al = *(const bf16x8*)&As_l[ml * 32 + quad * 8];
                #pragma unroll
                for (int jt = 0; jt < 4; ++jt) {
                    acc[it][jt] = __builtin_amdgcn_mfma_f32_16x16x32_bf16(ah, bh[jt], acc[it][jt], 0, 0, 0);
                    acc[it][jt] = __builtin_amdgcn_mfma_f32_16x16x32_bf16(ah, bl[jt], acc[it][jt], 0, 0, 0);
                    acc[it][jt] = __builtin_amdgcn_mfma_f32_16x16x32_bf16(al, bh[jt], acc[it][jt], 0, 0, 0);
                }
            }
            __syncthreads();
        }

        const bool isK = (wc == 0);
        const int colg = (isK ? 0 : C_EMB) + h * 64;
        float bb[4];
        #pragma unroll
        for (int jt = 0; jt < 4; ++jt) bb[jt] = bias[colg + jt * 16 + lrow];
        #pragma unroll
        for (int it = 0; it < 4; ++it)
            #pragma unroll
            for (int jt = 0; jt < 4; ++jt)
                #pragma unroll
                for (int r = 0; r < 4; ++r) {
                    float v = acc[it][jt][r] + bb[jt];
                    acc[it][jt][r] = isK ? elu1(v) : v;
                }

        if (isK) {
            #pragma unroll
            for (int jt = 0; jt < 4; ++jt) {
                float p = 0.0f;
                #pragma unroll
                for (int it = 0; it < 4; ++it)
                    #pragma unroll
                    for (int r = 0; r < 4; ++r) p += acc[it][jt][r];
                p += __shfl_xor(p, 16);
                p += __shfl_xor(p, 32);
                if (quad == 0)
                    atomicAdd(&Ksum[b * C_EMB + h * 64 + jt * 16 + lrow], p);
            }
            #pragma unroll
            for (int it = 0; it < 4; ++it)
                #pragma unroll
                for (int r = 0; r < 4; ++r) {
                    int s = tbase + it * 16 + quad * 4 + r;
                    float2 c0 = tab[s * 32 + lrow];
                    float2 c1 = tab[s * 32 + 16 + lrow];
                    float a0 = acc[it][0][r], a1 = acc[it][1][r];
                    float a2 = acc[it][2][r], a3 = acc[it][3][r];
                    acc[it][0][r] = a0 * c0.x - a2 * c0.y;
                    acc[it][2][r] = a2 * c0.x + a0 * c0.y;
                    acc[it][1][r] = a1 * c1.x - a3 * c1.y;
                    acc[it][3][r] = a3 * c1.x + a1 * c1.y;
                }
        }

        // transposed LDS: K_hi[64][136] @0, K_lo @8704, V_hi @17408, V_lo @26112
        unsigned short* Hd = smem + (isK ? 0 : 17408);
        unsigned short* Ld = Hd + 8704;
        #pragma unroll
        for (int jt = 0; jt < 4; ++jt) {
            int d = jt * 16 + lrow;
            #pragma unroll
            for (int it = 0; it < 4; ++it) {
                int t0loc = wr * 64 + it * 16 + quad * 4;
                ushort4 h4, l4;
                float v0 = acc[it][jt][0], v1 = acc[it][jt][1];
                float v2 = acc[it][jt][2], v3 = acc[it][jt][3];
                h4.x = bf16_rne(v0); l4.x = bf16_rne(v0 - bf16_to_f(h4.x));
                h4.y = bf16_rne(v1); l4.y = bf16_rne(v1 - bf16_to_f(h4.y));
                h4.z = bf16_rne(v2); l4.z = bf16_rne(v2 - bf16_to_f(h4.z));
                h4.w = bf16_rne(v3); l4.w = bf16_rne(v3 - bf16_to_f(h4.w));
                *(ushort4*)&Hd[d * 136 + t0loc] = h4;
                *(ushort4*)&Ld[d * 136 + t0loc] = l4;
            }
        }
    }
    __syncthreads();

    {
        const unsigned short* KH = smem;
        const unsigned short* KL = smem + 8704;
        const unsigned short* VH = smem + 17408;
        const unsigned short* VL = smem + 26112;
        const int mrow = w * 16 + lrow;
        f32x4 macc[4] = {};
        #pragma unroll
        for (int ks = 0; ks < 4; ++ks) {
            int kof = ks * 32 + quad * 8;
            bf16x8 vah = *(const bf16x8*)&VH[mrow * 136 + kof];
            bf16x8 val = *(const bf16x8*)&VL[mrow * 136 + kof];
            #pragma unroll
            for (int jt = 0; jt < 4; ++jt) {
                int nrow = jt * 16 + lrow;
                bf16x8 kbh = *(const bf16x8*)&KH[nrow * 136 + kof];
                bf16x8 kbl = *(const bf16x8*)&KL[nrow * 136 + kof];
                macc[jt] = __builtin_amdgcn_mfma_f32_16x16x32_bf16(vah, kbh, macc[jt], 0, 0, 0);
                macc[jt] = __builtin_amdgcn_mfma_f32_16x16x32_bf16(vah, kbl, macc[jt], 0, 0, 0);
                macc[jt] = __builtin_amdgcn_mfma_f32_16x16x32_bf16(val, kbh, macc[jt], 0, 0, 0);
            }
        }
        const int bh = b * NH + h;
        #pragma unroll
        for (int jt = 0; jt < 4; ++jt)
            #pragma unroll
            for (int r = 0; r < 4; ++r)
                atomicAdd(&Mt[((size_t)bh * 64 + w * 16 + quad * 4 + r) * 64 + jt * 16 + lrow],
                          macc[jt][r]);
    }
}

// ---------------------------------------------------------------------------
// Q GEMM, 128x64 tile (one head per block). grid (16 heads, 32 mtiles) = 512
// blocks. Wave w owns rows w*32..+31 of the tile. Epilogue: bias, elu+1,
// den in registers, RoPE, Qrot -> per-wave LDS, Y = (Qrot @ Mt^T)/den, bf16
// hi/lo stores. LDS 36 KB.
// ---------------------------------------------------------------------------
__global__ __launch_bounds__(256) void gemm_q(
    const unsigned short* __restrict__ Ah, const unsigned short* __restrict__ Al,
    const unsigned short* __restrict__ Bth, const unsigned short* __restrict__ Btl,
    const float* __restrict__ bias, const float2* __restrict__ tab,
    const float* __restrict__ Ksum, const float* __restrict__ Mt,
    unsigned short* __restrict__ Yh, unsigned short* __restrict__ Yl)
{
    // main loop uses [0,12288); epilogue reuses [0,18432) as per-wave Qrot
    __shared__ unsigned short smem[18432];
    const int h  = blockIdx.x;
    const int m0 = blockIdx.y * 128;
    f32x4 acc[2][4] = {};
    gemm_main_loop_64(Ah, Al, Bth, Btl, smem, m0, h * 64, acc);

    const int tid = threadIdx.x;
    const int w = tid >> 6, lane = tid & 63;
    const int quad = lane >> 4, lrow = lane & 15;
    const int b = m0 >> 11;
    const int tbase = (m0 & 2047) + w * 32;
    const int bh = b * NH + h;

    float bb[4];
    #pragma unroll
    for (int jt = 0; jt < 4; ++jt) bb[jt] = bias[h * 64 + jt * 16 + lrow];
    #pragma unroll
    for (int it = 0; it < 2; ++it)
        #pragma unroll
        for (int jt = 0; jt < 4; ++jt)
            #pragma unroll
            for (int r = 0; r < 4; ++r)
                acc[it][jt][r] = elu1(acc[it][jt][r] + bb[jt]);

    // den (pre-rope), kept in registers
    float ks[4], den_reg[2][4];
    #pragma unroll
    for (int jt = 0; jt < 4; ++jt) ks[jt] = Ksum[b * C_EMB + h * 64 + jt * 16 + lrow];
    #pragma unroll
    for (int it = 0; it < 2; ++it)
        #pragma unroll
        for (int r = 0; r < 4; ++r) {
            float p = acc[it][0][r] * ks[0] + acc[it][1][r] * ks[1]
                    + acc[it][2][r] * ks[2] + acc[it][3][r] * ks[3];
            p += __shfl_xor(p, 1);
            p += __shfl_xor(p, 2);
            p += __shfl_xor(p, 4);
            p += __shfl_xor(p, 8);
            den_reg[it][r] = p;
        }

    // RoPE in registers (pairs jt, jt^2)
    #pragma unroll
    for (int it = 0; it < 2; ++it)
        #pragma unroll
        for (int r = 0; r < 4; ++r) {
            int s = tbase + it * 16 + quad * 4 + r;
            float2 c0 = tab[s * 32 + lrow];
            float2 c1 = tab[s * 32 + 16 + lrow];
            float a0 = acc[it][0][r], a1 = acc[it][1][r];
            float a2 = acc[it][2][r], a3 = acc[it][3][r];
            acc[it][0][r] = a0 * c0.x - a2 * c0.y;
            acc[it][2][r] = a2 * c0.x + a0 * c0.y;
            acc[it][1][r] = a1 * c1.x - a3 * c1.y;
            acc[it][3][r] = a3 * c1.x + a1 * c1.y;
        }

    // Qrot -> per-wave LDS ([32 rows][72], hi then lo). Wave-private region:
    // main loop's last __syncthreads already drained cross-wave LDS reads.
    unsigned short* QH = smem + w * 4608;
    unsigned short* QL = QH + 2304;
    #pragma unroll
    for (int it = 0; it < 2; ++it)
        #pragma unroll
        for (int jt = 0; jt < 4; ++jt)
            #pragma unroll
            for (int r = 0; r < 4; ++r) {
                int tloc = it * 16 + quad * 4 + r;
                int d = jt * 16 + lrow;
                float v = acc[it][jt][r];
                unsigned short hh = bf16_rne(v);
                QH[tloc * 72 + d] = hh;
                QL[tloc * 72 + d] = bf16_rne(v - bf16_to_f(hh));
            }

    // Y = (Qrot @ Mt^T) / den
    f32x4 acc2[2][4] = {};
    #pragma unroll
    for (int kc = 0; kc < 2; ++kc) {
        bf16x8 mbh[4], mbl[4];
        #pragma unroll
        for (int jt2 = 0; jt2 < 4; ++jt2) {
            const float* mp = &Mt[((size_t)bh * 64 + jt2 * 16 + lrow) * 64 + kc * 32 + quad * 8];
            #pragma unroll
            for (int e = 0; e < 8; ++e) {
                float x = mp[e];
                unsigned short hh = bf16_rne(x);
                mbh[jt2][e] = (short)hh;
                mbl[jt2][e] = (short)bf16_rne(x - bf16_to_f(hh));
            }
        }
        #pragma unroll
        for (int it2 = 0; it2 < 2; ++it2) {
            int ro = (it2 * 16 + lrow) * 72 + kc * 32 + quad * 8;
            bf16x8 qh = *(const bf16x8*)&QH[ro];
            bf16x8 ql = *(const bf16x8*)&QL[ro];
            #pragma unroll
            for (int jt2 = 0; jt2 < 4; ++jt2) {
                acc2[it2][jt2] = __builtin_amdgcn_mfma_f32_16x16x32_bf16(qh, mbh[jt2], acc2[it2][jt2], 0, 0, 0);
                acc2[it2][jt2] = __builtin_amdgcn_mfma_f32_16x16x32_bf16(qh, mbl[jt2], acc2[it2][jt2], 0, 0, 0);
                acc2[it2][jt2] = __builtin_amdgcn_mfma_f32_16x16x32_bf16(ql, mbh[jt2], acc2[it2][jt2], 0, 0, 0);
            }
        }
    }

    // divide + bf16 hi/lo store
    #pragma unroll
    for (int it2 = 0; it2 < 2; ++it2)
        #pragma unroll
        for (int jt2 = 0; jt2 < 4; ++jt2)
            #pragma unroll
            for (int r = 0; r < 4; ++r) {
                float v = acc2[it2][jt2][r] / den_reg[it2][r];
                size_t o = ((size_t)(m0 + w * 32 + it2 * 16 + quad * 4 + r)) * C_EMB
                         + h * 64 + jt2 * 16 + lrow;
                unsigned short hh = bf16_rne(v);
                Yh[o] = hh;
                Yl[o] = bf16_rne(v - bf16_to_f(hh));
            }
}

// ---------------------------------------------------------------------------
// Output projection GEMM, 128x64 tile: out = Y @ proj_w + proj_b (fp32).
// grid (16 n-tiles, 32 m-tiles) = 512 blocks. LDS 24 KB.
// ---------------------------------------------------------------------------
__global__ __launch_bounds__(256) void gemm_out(
    const unsigned short* __restrict__ Ah, const unsigned short* __restrict__ Al,
    const unsigned short* __restrict__ Bth, const unsigned short* __restrict__ Btl,
    const float* __restrict__ bias, float* __restrict__ out)
{
    __shared__ unsigned short lds[12288];
    const int m0 = blockIdx.y * 128, n0 = blockIdx.x * 64;
    f32x4 acc[2][4] = {};
    gemm_main_loop_64(Ah, Al, Bth, Btl, lds, m0, n0, acc);

    const int tid = threadIdx.x;
    const int w = tid >> 6, lane = tid & 63;
    const int quad = lane >> 4, lrow = lane & 15;

    #pragma unroll
    for (int jt = 0; jt < 4; ++jt) {
        int gc = n0 + jt * 16 + lrow;
        float bb = bias[gc];
        #pragma unroll
        for (int it = 0; it < 2; ++it) {
            int grb = m0 + w * 32 + it * 16 + quad * 4;
            #pragma unroll
            for (int r = 0; r < 4; ++r)
                out[(size_t)(grb + r) * C_EMB + gc] = acc[it][jt][r] + bb;
        }
    }
}

// ---------------------------------------------------------------------------
extern "C" void kernel_launch(void* const* d_in, const int* in_sizes, int n_in,
                              void* d_out, int out_size, void* d_ws, size_t ws_size,
                              hipStream_t stream)
{
    const float* x      = (const float*)d_in[0];
    const float* memory = (const float*)d_in[1];
    const float* q_w    = (const float*)d_in[2];
    const float* q_b    = (const float*)d_in[3];
    const float* kv_w   = (const float*)d_in[4];
    const float* kv_b   = (const float*)d_in[5];
    const float* proj_w = (const float*)d_in[6];
    const float* proj_b = (const float*)d_in[7];

    if (ws_size < WS_FLOATS * sizeof(float)) return;

    float* ws = (float*)d_ws;
    unsigned short* xh   = (unsigned short*)(ws + OFF_XH);
    unsigned short* xl   = (unsigned short*)(ws + OFF_XL);
    unsigned short* mh   = (unsigned short*)(ws + OFF_MEMH);
    unsigned short* ml   = (unsigned short*)(ws + OFF_MEML);
    unsigned short* qwh  = (unsigned short*)(ws + OFF_QWH);
    unsigned short* qwl  = (unsigned short*)(ws + OFF_QWL);
    unsigned short* kvwh = (unsigned short*)(ws + OFF_KVWH);
    unsigned short* kvwl = (unsigned short*)(ws + OFF_KVWL);
    unsigned short* pwh  = (unsigned short*)(ws + OFF_PWH);
    unsigned short* pwl  = (unsigned short*)(ws + OFF_PWL);
    unsigned short* Yh   = (unsigned short*)(ws + OFF_YH);
    unsigned short* Yl   = (unsigned short*)(ws + OFF_YL);
    float*  Ksum = ws + OFF_KSUM;
    float*  Mm   = ws + OFF_MT;
    float2* tab  = (float2*)(ws + OFF_TAB);

    // One prep dispatch: splits + weight transposes + rope table + zero Ksum/Mt
    prep_kernel<<<PREP_BLOCKS, 256, 0, stream>>>(
        x, memory, q_w, kv_w, proj_w,
        xh, xl, mh, ml, qwh, qwl, kvwh, kvwl, pwh, pwl,
        tab, Ksum /* zero_base: Ksum+Mt contiguous */);

    // KV GEMM (+elu/Ksum/rope + fused Mt accumulate). No K/V global output.
    gemm_kv<<<dim3(16, 32), 256, 0, stream>>>(mh, ml, kvwh, kvwl, kv_b, tab, Ksum, Mm);
    // Q GEMM (+elu/den/rope + fused Y = Qrot·Mt^T/den) -> Yh/Yl. 512 blocks.
    gemm_q<<<dim3(16, 32), 256, 0, stream>>>(xh, xl, qwh, qwl, q_b, tab, Ksum, Mm, Yh, Yl);
    // out = Y @ proj_w + proj_b. 512 blocks.
    gemm_out<<<dim3(16, 32), 256, 0, stream>>>(Yh, Yl, pwh, pwl, proj_b, (float*)d_out);
}

// Round 7
// 235.284 us; speedup vs baseline: 2.6781x; 1.0557x over previous
//
#include <hip/hip_runtime.h>
#include <cstddef>
#include <cstdint>

// Problem constants
#define B_SZ  2
#define T_SEQ 2048
#define S_SEQ 2048
#define C_EMB 1024
#define NH    16
#define HD    64
#define KDIM  1024   // inner dim of the three big GEMMs

typedef __attribute__((ext_vector_type(8))) short bf16x8;
typedef __attribute__((ext_vector_type(4))) float f32x4;

// ---------------------------------------------------------------------------
// Workspace layout (float units).
// ---------------------------------------------------------------------------
#define OFF_XH    ((size_t)0)           // [4096,1024] ushort
#define OFF_XL    ((size_t)2097152)
#define OFF_MEMH  ((size_t)4194304)     // [4096,1024] ushort
#define OFF_MEML  ((size_t)6291456)
#define OFF_QWH   ((size_t)8388608)     // [1024,1024] ushort (transposed [N,K])
#define OFF_QWL   ((size_t)8912896)
#define OFF_KVWH  ((size_t)9437184)     // [2048,1024] ushort
#define OFF_KVWL  ((size_t)10485760)
#define OFF_PWH   ((size_t)11534336)    // [1024,1024] ushort
#define OFF_PWL   ((size_t)12058624)
#define OFF_KSUM  ((size_t)12582912)    // [2,1024]      (zeroed by prep)
#define OFF_MT    ((size_t)12584960)    // [32,64,64]    (zeroed by prep)
#define OFF_TAB   ((size_t)12716032)    // [2048,32] float2
#define OFF_YH    ((size_t)12847104)    // [4096,1024] ushort
#define OFF_YL    ((size_t)14944256)
#define WS_FLOATS ((size_t)17041408)    // ~68.2 MB

__device__ __forceinline__ float elu1(float v) {
    return v > 0.0f ? v + 1.0f : __expf(v);
}
__device__ __forceinline__ unsigned short bf16_rne(float x) {
    union { float f; unsigned int u; } v; v.f = x;
    unsigned int u = v.u;
    return (unsigned short)((u + 0x7FFFu + ((u >> 16) & 1u)) >> 16);
}
__device__ __forceinline__ float bf16_to_f(unsigned short h) {
    union { unsigned int u; float f; } v; v.u = ((unsigned int)h) << 16;
    return v.f;
}

// ---------------------------------------------------------------------------
// Unified prep kernel (block-range dispatch), unchanged.
// ---------------------------------------------------------------------------
#define PREP_BLOCKS 13064

__device__ __forceinline__ void split4_body(
    const float4* __restrict__ in, ushort4* __restrict__ hi,
    ushort4* __restrict__ lo, int i)
{
    float4 v = in[i];
    ushort4 h, l;
    h.x = bf16_rne(v.x); l.x = bf16_rne(v.x - bf16_to_f(h.x));
    h.y = bf16_rne(v.y); l.y = bf16_rne(v.y - bf16_to_f(h.y));
    h.z = bf16_rne(v.z); l.z = bf16_rne(v.z - bf16_to_f(h.z));
    h.w = bf16_rne(v.w); l.w = bf16_rne(v.w - bf16_to_f(h.w));
    hi[i] = h; lo[i] = l;
}

__device__ __forceinline__ void transpose_body(
    const float* __restrict__ W, unsigned short* __restrict__ Wth,
    unsigned short* __restrict__ Wtl, int K, int N, int bx, int by,
    float (*tile)[33])
{
    const int k0 = by * 32, n0 = bx * 32;
    const int tx = threadIdx.x & 31, ty = threadIdx.x >> 5;
    #pragma unroll
    for (int j = 0; j < 4; ++j)
        tile[ty + j * 8][tx] = W[(size_t)(k0 + ty + j * 8) * N + n0 + tx];
    __syncthreads();
    #pragma unroll
    for (int j = 0; j < 4; ++j) {
        float x = tile[tx][ty + j * 8];
        unsigned short h = bf16_rne(x);
        unsigned short l = bf16_rne(x - bf16_to_f(h));
        size_t o = (size_t)(n0 + ty + j * 8) * K + k0 + tx;
        Wth[o] = h; Wtl[o] = l;
    }
}

__global__ __launch_bounds__(256) void prep_kernel(
    const float* __restrict__ x, const float* __restrict__ memory,
    const float* __restrict__ q_w, const float* __restrict__ kv_w,
    const float* __restrict__ proj_w,
    unsigned short* __restrict__ xh, unsigned short* __restrict__ xl,
    unsigned short* __restrict__ mh, unsigned short* __restrict__ ml,
    unsigned short* __restrict__ qwh, unsigned short* __restrict__ qwl,
    unsigned short* __restrict__ kvwh, unsigned short* __restrict__ kvwl,
    unsigned short* __restrict__ pwh, unsigned short* __restrict__ pwl,
    float2* __restrict__ tab, float* __restrict__ zero_base)
{
    __shared__ float tile[32][33];
    const int bid = blockIdx.x;
    const int tid = threadIdx.x;
    if (bid < 4096) {
        split4_body((const float4*)x, (ushort4*)xh, (ushort4*)xl, bid * 256 + tid);
    } else if (bid < 8192) {
        split4_body((const float4*)memory, (ushort4*)mh, (ushort4*)ml, (bid - 4096) * 256 + tid);
    } else if (bid < 9216) {
        int i = bid - 8192;
        transpose_body(q_w, qwh, qwl, 1024, 1024, i & 31, i >> 5, tile);
    } else if (bid < 11264) {
        int i = bid - 9216;
        transpose_body(kv_w, kvwh, kvwl, 1024, 2048, i & 63, i >> 6, tile);
    } else if (bid < 12288) {
        int i = bid - 11264;
        transpose_body(proj_w, pwh, pwl, 1024, 1024, i & 31, i >> 5, tile);
    } else if (bid < 12544) {
        int idx = (bid - 12288) * 256 + tid;    // pos*32 + i
        int pos = idx >> 5, i = idx & 31;
        double invf = exp(-(double)i * (9.210340371976184 / 32.0));  // 10000^(-i/32)
        float arg = (float)((double)pos * invf);
        float sn, cs;
        sincosf(arg, &sn, &cs);
        tab[idx] = make_float2(cs, sn);
    } else {
        int idx = (bid - 12544) * 256 + tid;
        if (idx < 2048 + 131072) zero_base[idx] = 0.0f;   // Ksum + Mt
    }
}

// ---------------------------------------------------------------------------
// 128(M)x64(N) bf16x3 MFMA main loop, BK=64 as two 32-wide K-panels per
// barrier (each panel row-major stride 32 so global_load_lds's contiguous
// lane mapping holds). 4 waves: wave w owns rows w*32..w*32+31, all 64 cols.
// LDS (ushort units): As_h[0,8192) As_l[8192,16384) Bs_h[16384,20480)
// Bs_l[20480,24576) -- 48 KB. Fills acc[2][4].
// ---------------------------------------------------------------------------
__device__ __forceinline__ void gemm_main_loop_64(
    const unsigned short* __restrict__ Ah, const unsigned short* __restrict__ Al,
    const unsigned short* __restrict__ Bth, const unsigned short* __restrict__ Btl,
    unsigned short* lds, int m0, int n0, f32x4 acc[2][4])
{
    const int tid = threadIdx.x;
    const int w = tid >> 6, lane = tid & 63;
    const int quad = lane >> 4, lrow = lane & 15;
    const int srow = lane >> 2;
    const int scol = (lane & 3) * 8;

    const unsigned short* src = (w == 0) ? Ah : (w == 1) ? Al : (w == 2) ? Bth : Btl;
    const int rbase = (w < 2) ? m0 : n0;
    const unsigned short* gsrc = src + (size_t)(rbase + srow) * KDIM + scol;
    unsigned short* lbase = (w < 2) ? &lds[w * 8192] : &lds[16384 + (w - 2) * 4096];

    const unsigned short* As_h = lds;
    const unsigned short* As_l = lds + 8192;
    const unsigned short* Bs_h = lds + 16384;
    const unsigned short* Bs_l = lds + 20480;

    for (int k0 = 0; k0 < KDIM; k0 += 64) {
        if (w < 2) {
            // A: 128 rows x 2 panels, 8 instrs (16 rows) per panel
            #pragma unroll
            for (int p = 0; p < 2; ++p)
                #pragma unroll
                for (int i = 0; i < 8; ++i)
                    __builtin_amdgcn_global_load_lds(
                        (const __attribute__((address_space(1))) unsigned int*)(gsrc + (size_t)i * 16 * KDIM + k0 + p * 32),
                        (__attribute__((address_space(3))) unsigned int*)(lbase + p * 4096 + i * 512),
                        16, 0, 0);
        } else {
            // B: 64 rows x 2 panels, 4 instrs per panel
            #pragma unroll
            for (int p = 0; p < 2; ++p)
                #pragma unroll
                for (int i = 0; i < 4; ++i)
                    __builtin_amdgcn_global_load_lds(
                        (const __attribute__((address_space(1))) unsigned int*)(gsrc + (size_t)i * 16 * KDIM + k0 + p * 32),
                        (__attribute__((address_space(3))) unsigned int*)(lbase + p * 2048 + i * 512),
                        16, 0, 0);
        }
        __syncthreads();

        #pragma unroll
        for (int p = 0; p < 2; ++p) {
            bf16x8 bh[4], bl[4];
            #pragma unroll
            for (int jt = 0; jt < 4; ++jt) {
                int nl = jt * 16 + lrow;
                bh[jt] = *(const bf16x8*)&Bs_h[p * 2048 + nl * 32 + quad * 8];
                bl[jt] = *(const bf16x8*)&Bs_l[p * 2048 + nl * 32 + quad * 8];
            }
            #pragma unroll
            for (int it = 0; it < 2; ++it) {
                int ml = w * 32 + it * 16 + lrow;
                bf16x8 ah = *(const bf16x8*)&As_h[p * 4096 + ml * 32 + quad * 8];
                bf16x8 al = *(const bf16x8*)&As_l[p * 4096 + ml * 32 + quad * 8];
                #pragma unroll
                for (int jt = 0; jt < 4; ++jt) {
                    acc[it][jt] = __builtin_amdgcn_mfma_f32_16x16x32_bf16(ah, bh[jt], acc[it][jt], 0, 0, 0);
                    acc[it][jt] = __builtin_amdgcn_mfma_f32_16x16x32_bf16(ah, bl[jt], acc[it][jt], 0, 0, 0);
                    acc[it][jt] = __builtin_amdgcn_mfma_f32_16x16x32_bf16(al, bh[jt], acc[it][jt], 0, 0, 0);
                }
            }
        }
        __syncthreads();
    }
}

// ---------------------------------------------------------------------------
// KV GEMM: 128x128 head-paired tile, BK=64 (two 32-panels per barrier),
// fused elu/Ksum/rope + Mt accumulate. grid (16 heads, 32 mtiles).
// Main loop LDS: As_h[0,8192) As_l[8192,16384) Bs_h[16384,24576)
// Bs_l[24576,32768) (ushort units, panels of 4096). Epilogue reuses 34816.
// ---------------------------------------------------------------------------
__global__ __launch_bounds__(256) void gemm_kv(
    const unsigned short* __restrict__ Ah, const unsigned short* __restrict__ Al,
    const unsigned short* __restrict__ Bth, const unsigned short* __restrict__ Btl,
    const float* __restrict__ bias, const float2* __restrict__ tab,
    float* __restrict__ Ksum, float* __restrict__ Mt)
{
    __shared__ unsigned short smem[34816];
    const int tid = threadIdx.x;
    const int w = tid >> 6, lane = tid & 63;
    const int wr = w >> 1, wc = w & 1;
    const int quad = lane >> 4, lrow = lane & 15;
    const int h  = blockIdx.x;
    const int m0 = blockIdx.y * 128;
    const int b  = m0 >> 11;
    const int tbase = (m0 & 2047) + wr * 64;

    {
        const unsigned short* src = (w == 0) ? Ah : (w == 1) ? Al : (w == 2) ? Bth : Btl;
        const int srow = lane >> 2, scol = (lane & 3) * 8;
        const size_t rowbase = (w < 2) ? (size_t)(m0 + srow) : (size_t)(h * 64 + srow);
        const unsigned short* gsrc = src + rowbase * KDIM + scol;
        const size_t vskip = (w >= 2) ? (size_t)960 * KDIM : 0;
        unsigned short* lbase = &smem[w * 8192];
        const unsigned short* As_h = smem;
        const unsigned short* As_l = smem + 8192;
        const unsigned short* Bs_h = smem + 16384;
        const unsigned short* Bs_l = smem + 24576;

        f32x4 acc[4][4] = {};
        for (int k0 = 0; k0 < KDIM; k0 += 64) {
            #pragma unroll
            for (int p = 0; p < 2; ++p)
                #pragma unroll
                for (int i = 0; i < 8; ++i) {
                    size_t goff = (size_t)i * 16 * KDIM + k0 + p * 32 + ((i >= 4) ? vskip : 0);
                    __builtin_amdgcn_global_load_lds(
                        (const __attribute__((address_space(1))) unsigned int*)(gsrc + goff),
                        (__attribute__((address_space(3))) unsigned int*)(lbase + p * 4096 + i * 512),
                        16, 0, 0);
                }
            __syncthreads();
            #pragma unroll
            for (int p = 0; p < 2; ++p) {
                bf16x8 bh[4], bl[4];
                #pragma unroll
                for (int jt = 0; jt < 4; ++jt) {
                    int nl = wc * 64 + jt * 16 + lrow;
                    bh[jt] = *(const bf16x8*)&Bs_h[p * 4096 + nl * 32 + quad * 8];
                    bl[jt] = *(const bf16x8*)&Bs_l[p * 4096 + nl * 32 + quad * 8];
                }
                #pragma unroll
                for (int it = 0; it < 4; ++it) {
                    int ml = wr * 64 + it * 16 + lrow;
                    bf16x8 ah = *(const bf16x8*)&As_h[p * 4096 + ml * 32 + quad * 8];
                    bf16x8 al = *(const bf16x8*)&As_l[p * 4096 + ml * 32 + quad * 8];
                    #pragma unroll
                    for (int jt = 0; jt < 4; ++jt) {
                        acc[it][jt] = __builtin_amdgcn_mfma_f32_16x16x32_bf16(ah, bh[jt], acc[it][jt], 0, 0, 0);
                        acc[it][jt] = __builtin_amdgcn_mfma_f32_16x16x32_bf16(ah, bl[jt], acc[it][jt], 0, 0, 0);
                        acc[it][jt] = __builtin_amdgcn_mfma_f32_16x16x32_bf16(al, bh[jt], acc[it][jt], 0, 0, 0);
                    }
                }
            }
            __syncthreads();
        }

        const bool isK = (wc == 0);
        const int colg = (isK ? 0 : C_EMB) + h * 64;
        float bb[4];
        #pragma unroll
        for (int jt = 0; jt < 4; ++jt) bb[jt] = bias[colg + jt * 16 + lrow];
        #pragma unroll
        for (int it = 0; it < 4; ++it)
            #pragma unroll
            for (int jt = 0; jt < 4; ++jt)
                #pragma unroll
                for (int r = 0; r < 4; ++r) {
                    float v = acc[it][jt][r] + bb[jt];
                    acc[it][jt][r] = isK ? elu1(v) : v;
                }

        if (isK) {
            #pragma unroll
            for (int jt = 0; jt < 4; ++jt) {
                float p = 0.0f;
                #pragma unroll
                for (int it = 0; it < 4; ++it)
                    #pragma unroll
                    for (int r = 0; r < 4; ++r) p += acc[it][jt][r];
                p += __shfl_xor(p, 16);
                p += __shfl_xor(p, 32);
                if (quad == 0)
                    atomicAdd(&Ksum[b * C_EMB + h * 64 + jt * 16 + lrow], p);
            }
            #pragma unroll
            for (int it = 0; it < 4; ++it)
                #pragma unroll
                for (int r = 0; r < 4; ++r) {
                    int s = tbase + it * 16 + quad * 4 + r;
                    float2 c0 = tab[s * 32 + lrow];
                    float2 c1 = tab[s * 32 + 16 + lrow];
                    float a0 = acc[it][0][r], a1 = acc[it][1][r];
                    float a2 = acc[it][2][r], a3 = acc[it][3][r];
                    acc[it][0][r] = a0 * c0.x - a2 * c0.y;
                    acc[it][2][r] = a2 * c0.x + a0 * c0.y;
                    acc[it][1][r] = a1 * c1.x - a3 * c1.y;
                    acc[it][3][r] = a3 * c1.x + a1 * c1.y;
                }
        }

        // transposed LDS: K_hi[64][136] @0, K_lo @8704, V_hi @17408, V_lo @26112
        unsigned short* Hd = smem + (isK ? 0 : 17408);
        unsigned short* Ld = Hd + 8704;
        #pragma unroll
        for (int jt = 0; jt < 4; ++jt) {
            int d = jt * 16 + lrow;
            #pragma unroll
            for (int it = 0; it < 4; ++it) {
                int t0loc = wr * 64 + it * 16 + quad * 4;
                ushort4 h4, l4;
                float v0 = acc[it][jt][0], v1 = acc[it][jt][1];
                float v2 = acc[it][jt][2], v3 = acc[it][jt][3];
                h4.x = bf16_rne(v0); l4.x = bf16_rne(v0 - bf16_to_f(h4.x));
                h4.y = bf16_rne(v1); l4.y = bf16_rne(v1 - bf16_to_f(h4.y));
                h4.z = bf16_rne(v2); l4.z = bf16_rne(v2 - bf16_to_f(h4.z));
                h4.w = bf16_rne(v3); l4.w = bf16_rne(v3 - bf16_to_f(h4.w));
                *(ushort4*)&Hd[d * 136 + t0loc] = h4;
                *(ushort4*)&Ld[d * 136 + t0loc] = l4;
            }
        }
    }
    __syncthreads();

    {
        const unsigned short* KH = smem;
        const unsigned short* KL = smem + 8704;
        const unsigned short* VH = smem + 17408;
        const unsigned short* VL = smem + 26112;
        const int mrow = w * 16 + lrow;
        f32x4 macc[4] = {};
        #pragma unroll
        for (int ks = 0; ks < 4; ++ks) {
            int kof = ks * 32 + quad * 8;
            bf16x8 vah = *(const bf16x8*)&VH[mrow * 136 + kof];
            bf16x8 val = *(const bf16x8*)&VL[mrow * 136 + kof];
            #pragma unroll
            for (int jt = 0; jt < 4; ++jt) {
                int nrow = jt * 16 + lrow;
                bf16x8 kbh = *(const bf16x8*)&KH[nrow * 136 + kof];
                bf16x8 kbl = *(const bf16x8*)&KL[nrow * 136 + kof];
                macc[jt] = __builtin_amdgcn_mfma_f32_16x16x32_bf16(vah, kbh, macc[jt], 0, 0, 0);
                macc[jt] = __builtin_amdgcn_mfma_f32_16x16x32_bf16(vah, kbl, macc[jt], 0, 0, 0);
                macc[jt] = __builtin_amdgcn_mfma_f32_16x16x32_bf16(val, kbh, macc[jt], 0, 0, 0);
            }
        }
        const int bh = b * NH + h;
        #pragma unroll
        for (int jt = 0; jt < 4; ++jt)
            #pragma unroll
            for (int r = 0; r < 4; ++r)
                atomicAdd(&Mt[((size_t)bh * 64 + w * 16 + quad * 4 + r) * 64 + jt * 16 + lrow],
                          macc[jt][r]);
    }
}

// ---------------------------------------------------------------------------
// Q GEMM, 128x64 tile (one head per block), BK=64 loop. grid (16, 32) = 512
// blocks. Epilogue unchanged: bias, elu+1, den in regs, RoPE, per-wave Qrot
// LDS, Y = (Qrot @ Mt^T)/den, bf16 hi/lo stores.
// ---------------------------------------------------------------------------
__global__ __launch_bounds__(256) void gemm_q(
    const unsigned short* __restrict__ Ah, const unsigned short* __restrict__ Al,
    const unsigned short* __restrict__ Bth, const unsigned short* __restrict__ Btl,
    const float* __restrict__ bias, const float2* __restrict__ tab,
    const float* __restrict__ Ksum, const float* __restrict__ Mt,
    unsigned short* __restrict__ Yh, unsigned short* __restrict__ Yl)
{
    // main loop uses [0,24576); epilogue reuses [0,18432) as per-wave Qrot
    __shared__ unsigned short smem[24576];
    const int h  = blockIdx.x;
    const int m0 = blockIdx.y * 128;
    f32x4 acc[2][4] = {};
    gemm_main_loop_64(Ah, Al, Bth, Btl, smem, m0, h * 64, acc);

    const int tid = threadIdx.x;
    const int w = tid >> 6, lane = tid & 63;
    const int quad = lane >> 4, lrow = lane & 15;
    const int b = m0 >> 11;
    const int tbase = (m0 & 2047) + w * 32;
    const int bh = b * NH + h;

    float bb[4];
    #pragma unroll
    for (int jt = 0; jt < 4; ++jt) bb[jt] = bias[h * 64 + jt * 16 + lrow];
    #pragma unroll
    for (int it = 0; it < 2; ++it)
        #pragma unroll
        for (int jt = 0; jt < 4; ++jt)
            #pragma unroll
            for (int r = 0; r < 4; ++r)
                acc[it][jt][r] = elu1(acc[it][jt][r] + bb[jt]);

    // den (pre-rope), kept in registers
    float ks[4], den_reg[2][4];
    #pragma unroll
    for (int jt = 0; jt < 4; ++jt) ks[jt] = Ksum[b * C_EMB + h * 64 + jt * 16 + lrow];
    #pragma unroll
    for (int it = 0; it < 2; ++it)
        #pragma unroll
        for (int r = 0; r < 4; ++r) {
            float p = acc[it][0][r] * ks[0] + acc[it][1][r] * ks[1]
                    + acc[it][2][r] * ks[2] + acc[it][3][r] * ks[3];
            p += __shfl_xor(p, 1);
            p += __shfl_xor(p, 2);
            p += __shfl_xor(p, 4);
            p += __shfl_xor(p, 8);
            den_reg[it][r] = p;
        }

    // RoPE in registers (pairs jt, jt^2)
    #pragma unroll
    for (int it = 0; it < 2; ++it)
        #pragma unroll
        for (int r = 0; r < 4; ++r) {
            int s = tbase + it * 16 + quad * 4 + r;
            float2 c0 = tab[s * 32 + lrow];
            float2 c1 = tab[s * 32 + 16 + lrow];
            float a0 = acc[it][0][r], a1 = acc[it][1][r];
            float a2 = acc[it][2][r], a3 = acc[it][3][r];
            acc[it][0][r] = a0 * c0.x - a2 * c0.y;
            acc[it][2][r] = a2 * c0.x + a0 * c0.y;
            acc[it][1][r] = a1 * c1.x - a3 * c1.y;
            acc[it][3][r] = a3 * c1.x + a1 * c1.y;
        }

    // Qrot -> per-wave LDS ([32 rows][72], hi then lo). Wave-private region;
    // main loop's final __syncthreads drained cross-wave LDS reads.
    unsigned short* QH = smem + w * 4608;
    unsigned short* QL = QH + 2304;
    #pragma unroll
    for (int it = 0; it < 2; ++it)
        #pragma unroll
        for (int jt = 0; jt < 4; ++jt)
            #pragma unroll
            for (int r = 0; r < 4; ++r) {
                int tloc = it * 16 + quad * 4 + r;
                int d = jt * 16 + lrow;
                float v = acc[it][jt][r];
                unsigned short hh = bf16_rne(v);
                QH[tloc * 72 + d] = hh;
                QL[tloc * 72 + d] = bf16_rne(v - bf16_to_f(hh));
            }

    // Y = (Qrot @ Mt^T) / den
    f32x4 acc2[2][4] = {};
    #pragma unroll
    for (int kc = 0; kc < 2; ++kc) {
        bf16x8 mbh[4], mbl[4];
        #pragma unroll
        for (int jt2 = 0; jt2 < 4; ++jt2) {
            const float* mp = &Mt[((size_t)bh * 64 + jt2 * 16 + lrow) * 64 + kc * 32 + quad * 8];
            #pragma unroll
            for (int e = 0; e < 8; ++e) {
                float x = mp[e];
                unsigned short hh = bf16_rne(x);
                mbh[jt2][e] = (short)hh;
                mbl[jt2][e] = (short)bf16_rne(x - bf16_to_f(hh));
            }
        }
        #pragma unroll
        for (int it2 = 0; it2 < 2; ++it2) {
            int ro = (it2 * 16 + lrow) * 72 + kc * 32 + quad * 8;
            bf16x8 qh = *(const bf16x8*)&QH[ro];
            bf16x8 ql = *(const bf16x8*)&QL[ro];
            #pragma unroll
            for (int jt2 = 0; jt2 < 4; ++jt2) {
                acc2[it2][jt2] = __builtin_amdgcn_mfma_f32_16x16x32_bf16(qh, mbh[jt2], acc2[it2][jt2], 0, 0, 0);
                acc2[it2][jt2] = __builtin_amdgcn_mfma_f32_16x16x32_bf16(qh, mbl[jt2], acc2[it2][jt2], 0, 0, 0);
                acc2[it2][jt2] = __builtin_amdgcn_mfma_f32_16x16x32_bf16(ql, mbh[jt2], acc2[it2][jt2], 0, 0, 0);
            }
        }
    }

    // divide + bf16 hi/lo store
    #pragma unroll
    for (int it2 = 0; it2 < 2; ++it2)
        #pragma unroll
        for (int jt2 = 0; jt2 < 4; ++jt2)
            #pragma unroll
            for (int r = 0; r < 4; ++r) {
                float v = acc2[it2][jt2][r] / den_reg[it2][r];
                size_t o = ((size_t)(m0 + w * 32 + it2 * 16 + quad * 4 + r)) * C_EMB
                         + h * 64 + jt2 * 16 + lrow;
                unsigned short hh = bf16_rne(v);
                Yh[o] = hh;
                Yl[o] = bf16_rne(v - bf16_to_f(hh));
            }
}

// ---------------------------------------------------------------------------
// Output projection GEMM, 128x64 tile, BK=64: out = Y @ proj_w + proj_b.
// grid (16 n-tiles, 32 m-tiles) = 512 blocks. LDS 48 KB.
// ---------------------------------------------------------------------------
__global__ __launch_bounds__(256) void gemm_out(
    const unsigned short* __restrict__ Ah, const unsigned short* __restrict__ Al,
    const unsigned short* __restrict__ Bth, const unsigned short* __restrict__ Btl,
    const float* __restrict__ bias, float* __restrict__ out)
{
    __shared__ unsigned short lds[24576];
    const int m0 = blockIdx.y * 128, n0 = blockIdx.x * 64;
    f32x4 acc[2][4] = {};
    gemm_main_loop_64(Ah, Al, Bth, Btl, lds, m0, n0, acc);

    const int tid = threadIdx.x;
    const int w = tid >> 6, lane = tid & 63;
    const int quad = lane >> 4, lrow = lane & 15;

    #pragma unroll
    for (int jt = 0; jt < 4; ++jt) {
        int gc = n0 + jt * 16 + lrow;
        float bb = bias[gc];
        #pragma unroll
        for (int it = 0; it < 2; ++it) {
            int grb = m0 + w * 32 + it * 16 + quad * 4;
            #pragma unroll
            for (int r = 0; r < 4; ++r)
                out[(size_t)(grb + r) * C_EMB + gc] = acc[it][jt][r] + bb;
        }
    }
}

// ---------------------------------------------------------------------------
extern "C" void kernel_launch(void* const* d_in, const int* in_sizes, int n_in,
                              void* d_out, int out_size, void* d_ws, size_t ws_size,
                              hipStream_t stream)
{
    const float* x      = (const float*)d_in[0];
    const float* memory = (const float*)d_in[1];
    const float* q_w    = (const float*)d_in[2];
    const float* q_b    = (const float*)d_in[3];
    const float* kv_w   = (const float*)d_in[4];
    const float* kv_b   = (const float*)d_in[5];
    const float* proj_w = (const float*)d_in[6];
    const float* proj_b = (const float*)d_in[7];

    if (ws_size < WS_FLOATS * sizeof(float)) return;

    float* ws = (float*)d_ws;
    unsigned short* xh   = (unsigned short*)(ws + OFF_XH);
    unsigned short* xl   = (unsigned short*)(ws + OFF_XL);
    unsigned short* mh   = (unsigned short*)(ws + OFF_MEMH);
    unsigned short* ml   = (unsigned short*)(ws + OFF_MEML);
    unsigned short* qwh  = (unsigned short*)(ws + OFF_QWH);
    unsigned short* qwl  = (unsigned short*)(ws + OFF_QWL);
    unsigned short* kvwh = (unsigned short*)(ws + OFF_KVWH);
    unsigned short* kvwl = (unsigned short*)(ws + OFF_KVWL);
    unsigned short* pwh  = (unsigned short*)(ws + OFF_PWH);
    unsigned short* pwl  = (unsigned short*)(ws + OFF_PWL);
    unsigned short* Yh   = (unsigned short*)(ws + OFF_YH);
    unsigned short* Yl   = (unsigned short*)(ws + OFF_YL);
    float*  Ksum = ws + OFF_KSUM;
    float*  Mm   = ws + OFF_MT;
    float2* tab  = (float2*)(ws + OFF_TAB);

    // One prep dispatch: splits + weight transposes + rope table + zero Ksum/Mt
    prep_kernel<<<PREP_BLOCKS, 256, 0, stream>>>(
        x, memory, q_w, kv_w, proj_w,
        xh, xl, mh, ml, qwh, qwl, kvwh, kvwl, pwh, pwl,
        tab, Ksum /* zero_base: Ksum+Mt contiguous */);

    // KV GEMM (+elu/Ksum/rope + fused Mt accumulate). No K/V global output.
    gemm_kv<<<dim3(16, 32), 256, 0, stream>>>(mh, ml, kvwh, kvwl, kv_b, tab, Ksum, Mm);
    // Q GEMM (+elu/den/rope + fused Y = Qrot·Mt^T/den) -> Yh/Yl. 512 blocks.
    gemm_q<<<dim3(16, 32), 256, 0, stream>>>(xh, xl, qwh, qwl, q_b, tab, Ksum, Mm, Yh, Yl);
    // out = Y @ proj_w + proj_b. 512 blocks.
    gemm_out<<<dim3(16, 32), 256, 0, stream>>>(Yh, Yl, pwh, pwl, proj_b, (float*)d_out);
}